// Round 10
// baseline (3750.798 us; speedup 1.0000x reference)
//
#include <hip/hip_runtime.h>
#include <hip/hip_bf16.h>
#include <math.h>

#define MINV 1e-15f
#define MAXN 0.996f   // (1 - 4e-3) / sqrt(c), c = 1

__device__ __forceinline__ float artanh_f(float x){
    x = fminf(fmaxf(x, -1.0f + 1e-7f), 1.0f - 1e-7f);
    return 0.5f * (log1pf(x) - log1pf(-x));
}

template<int NW>
__device__ __forceinline__ float block_sum(float v, float* sm){
    #pragma unroll
    for(int o=32;o>0;o>>=1) v += __shfl_down(v,o);
    int lane = threadIdx.x & 63, w = threadIdx.x >> 6;
    if(lane==0) sm[w] = v;
    __syncthreads();
    if(w==0){
        float t = (lane<NW)? sm[lane] : 0.0f;
        #pragma unroll
        for(int o=32;o>0;o>>=1) t += __shfl_down(t,o);
        if(lane==0) sm[0] = t;
    }
    __syncthreads();
    float r = sm[0];
    __syncthreads();
    return r;
}

// ---- LDS-tree reductions for 256-thread blocks ----
__device__ __forceinline__ float tree_sum256(float v, float* red){
    int tid = threadIdx.x;
    __syncthreads();
    red[tid] = v;
    __syncthreads();
    for(int o = 128; o > 0; o >>= 1){
        if(tid < o) red[tid] += red[tid + o];
        __syncthreads();
    }
    return red[0];
}
__device__ __forceinline__ float tree_max256(float v, float* red){
    int tid = threadIdx.x;
    __syncthreads();
    red[tid] = v;
    __syncthreads();
    for(int o = 128; o > 0; o >>= 1){
        if(tid < o) red[tid] = fmaxf(red[tid], red[tid + o]);
        __syncthreads();
    }
    return red[0];
}

// ---- per-(b,d) column stats over the 512 positions (s_t / c_t proj+logmap) ----
__global__ void k_colnorm(const float* __restrict__ Srep, const float* __restrict__ Crep,
                          float* scale_s, float* g_s, float* scale_c, float* g_c){
    int b = blockIdx.x;
    bool isC = (blockIdx.y == 1);
    const float* X = isC ? Crep : Srep;
    float* sc = isC ? scale_c : scale_s;
    float* gg = isC ? g_c : g_s;
    int d = threadIdx.x & 127, grp = threadIdx.x >> 7;
    float acc = 0.f;
    if(d < 100){
        const float* base = X + (size_t)b*512*100 + d;
        for(int s = grp; s < 512; s += 4){ float x = base[(size_t)s*100]; acc += x*x; }
    }
    __shared__ float sm[4][128];
    sm[grp][d] = acc;
    __syncthreads();
    if(grp == 0){
        if(d < 100){
            float tot = sm[0][d]+sm[1][d]+sm[2][d]+sm[3][d];
            float n1 = fmaxf(sqrtf(tot), MINV);
            float scale = (n1 > MAXN) ? MAXN/n1 : 1.0f;
            float pn = fminf(n1, MAXN);
            sc[b*128+d] = scale;
            gg[b*128+d] = artanh_f(pn)/pn * scale;
        } else {
            sc[b*128+d] = 0.f;
            gg[b*128+d] = 0.f;
        }
    }
}

// ---- per-row (over D=100) stats: scaled norm (for matvec) + raw norm (for Wl) ----
__global__ void k_rowstats(const float* __restrict__ Srep, const float* __restrict__ Crep,
                           const float* __restrict__ scale_s, const float* __restrict__ scale_c,
                           float* xnsc_s, float* xnsc_c, float* xnraw_c){
    int row = blockIdx.x;               // b*512 + s
    bool isC = (blockIdx.y == 1);
    const float* X = (isC ? Crep : Srep) + (size_t)row*100;
    const float* sc = (isC ? scale_c : scale_s) + (size_t)(row >> 9)*128;
    int d = threadIdx.x;
    float xr = 0.f, xs = 0.f;
    if(d < 100){ float v = X[d]; xr = v*v; float w = sc[d]*v; xs = w*w; }
    __shared__ float sm[2];
    float r2 = block_sum<2>(xr, sm);
    float s2 = block_sum<2>(xs, sm);
    if(threadIdx.x == 0){
        float nr = fmaxf(sqrtf(r2), MINV);
        float ns = fmaxf(sqrtf(s2), MINV);
        if(isC){ xnsc_c[row] = ns; xnraw_c[row] = nr; }
        else   { xnsc_s[row] = ns; }
    }
}

// ---- Wl matvec + mobius finalize + proj + logmap + fold g_s -> A1g [B,512,100] ----
__global__ void k_mv_wl(const float* __restrict__ Crep, const float* __restrict__ Wl,
                        const float* __restrict__ xnraw_c, const float* __restrict__ g_s,
                        float* __restrict__ A1g){
    int row = blockIdx.x;            // b*512 + t
    int b = row >> 9;
    __shared__ float xr[100];
    __shared__ float sm[2];
    int i = threadIdx.x;             // 0..127
    if(i < 100) xr[i] = Crep[(size_t)row*100 + i];
    __syncthreads();
    float mx = 0.f;
    if(i < 100){
        const float* w = Wl + (size_t)i*100;
        for(int d = 0; d < 100; d++) mx = fmaf(w[d], xr[d], mx);
    }
    float ss = block_sum<2>((i < 100) ? mx*mx : 0.f, sm);
    float mxn = fmaxf(sqrtf(ss), MINV);
    float xn = xnraw_c[row];
    float t1 = tanhf(mxn/xn * artanh_f(xn));
    float ps = (t1 > MAXN) ? MAXN/t1 : 1.0f;
    float m = fmaxf(fminf(t1, MAXN), MINV);
    float q = (t1/mxn) * ps * (artanh_f(m)/m);
    if(i < 100) A1g[(size_t)row*100 + i] = q * mx * g_s[b*128 + i];
}

// ---- Ws/Wc matvec on scaled rep + mobius finalize, write transposed [B,K,S] ----
__global__ void k_mv_w(const float* __restrict__ rep, const float* __restrict__ scale,
                       const float* __restrict__ xnsc, const float* __restrict__ W,
                       float* __restrict__ Out){
    int row = blockIdx.x;            // b*512 + s
    int b = row >> 9, s = row & 511;
    __shared__ float xr[100];
    __shared__ float sm[2];
    int k = threadIdx.x;             // 0..127
    if(k < 100) xr[k] = rep[(size_t)row*100 + k] * scale[b*128 + k];
    __syncthreads();
    float mx = 0.f;
    const float* w = W + (size_t)k*100;
    for(int d = 0; d < 100; d++) mx = fmaf(w[d], xr[d], mx);
    float ss = block_sum<2>(mx*mx, sm);
    float mxn = fmaxf(sqrtf(ss), MINV);
    float xn = xnsc[row];
    float t1 = tanhf(mxn/xn * artanh_f(xn));
    float mult = t1/mxn;
    Out[(size_t)b*65536 + (size_t)k*512 + s] = mx * mult;
}

// ---- proj rows (len 512) in place + store logmap factor ----
__global__ void e3_projrow(float* __restrict__ X, float* __restrict__ lf){
    int row = blockIdx.x;
    float* p = X + (size_t)row*512;
    int t = threadIdx.x;
    float v0 = p[t], v1 = p[t+256];
    __shared__ float sm[4];
    float ss = block_sum<4>(v0*v0 + v1*v1, sm);
    float n = fmaxf(sqrtf(ss), MINV);
    if(n > MAXN){ float ps = MAXN/n; p[t] = v0*ps; p[t+256] = v1*ps; }
    float m = fminf(n, MAXN);
    if(t == 0) lf[row] = artanh_f(m)/m;
}

// ---- L row: A1g[t,:] @ logmapST, tanh, expmap0+proj+logmap0 -> bf16 L_e[b,t,:] ----
__global__ void k_L(const float* __restrict__ A1g, const float* __restrict__ Srep,
                    __hip_bfloat16* __restrict__ L_e){
    int row = blockIdx.x;            // b*512 + t
    int b = row >> 9;
    __shared__ float ar[100];
    __shared__ float sm[8];
    int s = threadIdx.x;             // 0..511
    if(s < 100) ar[s] = A1g[(size_t)row*100 + s];
    __syncthreads();
    const float* sr = Srep + (size_t)b*512*100 + (size_t)s*100;
    float acc = 0.f;
    for(int d = 0; d < 100; d++) acc = fmaf(ar[d], sr[d], acc);
    float v = tanhf(acc);
    float ss = block_sum<8>(v*v, sm);
    float un = fmaxf(sqrtf(ss), MINV);
    float pn = fminf(tanhf(un), MAXN);
    float f = artanh_f(pn)/un;
    L_e[(size_t)row*512 + s] = __float2bfloat16(f*v);
}

// ---- H row: (lf*Ha_log) @ L_e(^T) -> expmap0+proj -> mobius_add with Ha_chain
//      -> proj -> logmap0 -> tanh -> expmap0 -> proj -> Hfin ----
template<int NT>
__global__ void k_Hrow(const float* __restrict__ Ha_log_src, const float* __restrict__ lf_log,
                       const __hip_bfloat16* __restrict__ L_e,
                       const float* __restrict__ Ha_chain,
                       float* __restrict__ Hfin){
    int k = blockIdx.x, b = blockIdx.y;   // grid (128, 128)
    __shared__ float ar[512];
    __shared__ float sm[8];
    int t = threadIdx.x;
    size_t rowoff = (size_t)b*65536 + (size_t)k*512;
    float lfv = lf_log[b*128 + k];
    ar[t] = Ha_log_src[rowoff + t] * lfv;
    __syncthreads();
    const __hip_bfloat16* Lb = L_e + (size_t)b*262144;
    float acc = 0.f;
    if(NT){
        const __hip_bfloat16* lr = Lb + (size_t)t*512;
        for(int s2 = 0; s2 < 512; s2++) acc = fmaf(ar[s2], __bfloat162float(lr[s2]), acc);
    } else {
        for(int t2 = 0; t2 < 512; t2++) acc = fmaf(ar[t2], __bfloat162float(Lb[(size_t)t2*512 + t]), acc);
    }
    float ss = block_sum<8>(acc*acc, sm);
    float un = fmaxf(sqrtf(ss), MINV);
    float y = fminf(tanhf(un), MAXN)/un * acc;
    float x = Ha_chain[rowoff + t];
    float x2 = block_sum<8>(x*x, sm);
    float y2 = block_sum<8>(y*y, sm);
    float xy = block_sum<8>(x*y, sm);
    float a  = 1.f + 2.f*xy + y2;
    float bb = 1.f - x2;
    float den = fmaxf(1.f + 2.f*xy + x2*y2, MINV);
    float z = (a*x + bb*y)/den;
    float zz = block_sum<8>(z*z, sm);
    float n = fmaxf(sqrtf(zz), MINV);
    float ps = (n > MAXN) ? MAXN/n : 1.f;
    float mm = fminf(n, MAXN);
    float lf2 = artanh_f(mm)/mm * ps;
    float v = tanhf(lf2*z);
    float vv = block_sum<8>(v*v, sm);
    float un2 = fmaxf(sqrtf(vv), MINV);
    float f2 = fminf(tanhf(un2), MAXN)/un2;
    Hfin[rowoff + t] = f2*v;
}

// ---- attention: wh-matvec + proj + logmap + softmax + expmap + proj (f32 out) ----
__global__ void att2(const float* __restrict__ H, const float* __restrict__ wh,
                     float* __restrict__ alog, float* __restrict__ outAtt){
    int b = blockIdx.x;
    int tid = threadIdx.x;              // 0..255
    __shared__ float whl[128];
    __shared__ float red[256];
    if(tid < 128) whl[tid] = wh[tid];
    __syncthreads();
    float res2[2];
    #pragma unroll
    for(int h = 0; h < 2; h++){
        int s = tid + h*256;
        const float* hp = H + (size_t)b*65536 + s;
        float mx = 0.f, x2 = 0.f;
        for(int k = 0; k < 128; k++){
            float v = hp[(size_t)k*512];
            mx = fmaf(whl[k], v, mx);
            x2 = fmaf(v, v, x2);
        }
        float xn  = fmaxf(sqrtf(x2), MINV);
        float mxn = fmaxf(fabsf(mx), MINV);
        float t1 = tanhf(mxn/xn * artanh_f(xn));
        res2[h] = t1 * (mx/mxn);
    }
    float rr = tree_sum256(res2[0]*res2[0] + res2[1]*res2[1], red);
    float n = fmaxf(sqrtf(rr), MINV);
    float ps = (n > MAXN) ? MAXN/n : 1.f;
    float m = fminf(n, MAXN);
    float lfw = artanh_f(m)/m * ps;
    float w0 = lfw*res2[0], w1 = lfw*res2[1];
    float wmax = tree_max256(fmaxf(w0, w1), red);
    float e0 = expf(w0 - wmax), e1 = expf(w1 - wmax);
    float es = tree_sum256(e0 + e1, red);
    float p0 = e0/es, p1 = e1/es;
    float pp = tree_sum256(p0*p0 + p1*p1, red);
    float un = fmaxf(sqrtf(pp), MINV);
    float th = tanhf(un);
    float f = fminf(th, MAXN)/un;
    float A0 = f*p0, A1 = f*p1;
    outAtt[b*512 + tid]       = A0;     // f32 store
    outAtt[b*512 + tid + 256] = A1;
    float m2 = fmaxf(fminf(th, MAXN), MINV);
    float fl = artanh_f(m2)/m2;
    alog[b*512 + tid]       = fl*A0;
    alog[b*512 + tid + 256] = fl*A1;
}

// ---- co kernel: both co_s and co_c; recomputes logmap0(rep) factors inline (f32 out) ----
__global__ void co2(const float* __restrict__ Srep, const float* __restrict__ Crep,
                    const float* __restrict__ alog_s, const float* __restrict__ alog_c,
                    float* __restrict__ out){
    int b = blockIdx.x, tid = threadIdx.x;   // 256 threads
    __shared__ float ws_[512], wc_[512];
    #pragma unroll
    for(int h = 0; h < 2; h++){
        int s = tid + h*256;
        const float* sp = Srep + (size_t)(b*512 + s)*100;
        const float* cp = Crep + (size_t)(b*512 + s)*100;
        float s2 = 0.f, c2 = 0.f;
        for(int d = 0; d < 100; d++){
            float a = sp[d]; s2 = fmaf(a, a, s2);
            float e = cp[d]; c2 = fmaf(e, e, c2);
        }
        float nsr = fmaxf(sqrtf(s2), MINV);
        float ncr = fmaxf(sqrtf(c2), MINV);
        ws_[s] = alog_s[b*512 + s] * (artanh_f(nsr)/nsr);
        wc_[s] = alog_c[b*512 + s] * (artanh_f(ncr)/ncr);
    }
    __syncthreads();
    if(tid < 100){
        float acc = 0.f;
        const float* rp = Srep + (size_t)b*51200 + tid;
        for(int s = 0; s < 512; s++) acc = fmaf(ws_[s], rp[(size_t)s*100], acc);
        out[b*200 + tid] = acc;             // f32 store
    } else if(tid >= 128 && tid < 228){
        int d = tid - 128;
        float acc = 0.f;
        const float* rp = Crep + (size_t)b*51200 + d;
        for(int s = 0; s < 512; s++) acc = fmaf(wc_[s], rp[(size_t)s*100], acc);
        out[b*200 + 100 + d] = acc;         // f32 store
    }
}

// ---- diagnostic fill (f32) ----
__global__ void k_fill(float* out, int n, float v){
    int i = blockIdx.x*256 + threadIdx.x;
    if(i < n) out[i] = v;
}

extern "C" void kernel_launch(void* const* d_in, const int* in_sizes, int n_in,
                              void* d_out, int out_size, void* d_ws, size_t ws_size,
                              hipStream_t stream)
{
    const float* Srep = (const float*)d_in[0];   // sentence_rep
    const float* Crep = (const float*)d_in[1];   // comment_rep
    const float* Wl   = (const float*)d_in[2];
    const float* Wc   = (const float*)d_in[3];
    const float* Ws   = (const float*)d_in[4];
    const float* whs  = (const float*)d_in[5];
    const float* whc  = (const float*)d_in[6];
    float* out = (float*)d_out;                  // OUTPUT IS FLOAT32 (round-9 finding)

    bool ok = (n_in == 7) &&
              in_sizes[0] == 6553600 && in_sizes[1] == 6553600 &&
              in_sizes[2] == 10000   && in_sizes[3] == 12800 &&
              in_sizes[4] == 12800   && in_sizes[5] == 128 && in_sizes[6] == 128 &&
              out_size == 156672;
    if(!ok){
        k_fill<<<(out_size+255)/256, 256, 0, stream>>>(out, out_size, 1.0f);
        return;
    }

    const size_t L_E_BYTES  = (size_t)128*512*512*2;
    const size_t A1G_ELTS   = (size_t)128*512*100;
    const size_t HBUF_ELTS  = (size_t)128*128*512;
    const size_t SMALL_ELTS = 6*16384 + 7*65536;
    const size_t REQ = L_E_BYTES + (A1G_ELTS + 4*HBUF_ELTS + SMALL_ELTS)*4;
    if(ws_size < REQ){
        k_fill<<<(out_size+255)/256, 256, 0, stream>>>(out, out_size, -1.0f);
        return;
    }

    char* base = (char*)d_ws;
    __hip_bfloat16* L_e = (__hip_bfloat16*)base;
    float* fbase = (float*)(base + L_E_BYTES);
    size_t o = 0;
    float* A1g    = fbase + o; o += A1G_ELTS;
    float* Hsa    = fbase + o; o += HBUF_ELTS;
    float* Hsb0   = fbase + o; o += HBUF_ELTS;
    float* Hs_fin = fbase + o; o += HBUF_ELTS;
    float* Hc_fin = fbase + o; o += HBUF_ELTS;
    float* scale_s = fbase + o; o += 16384;
    float* g_s     = fbase + o; o += 16384;
    float* scale_c = fbase + o; o += 16384;
    float* g_c     = fbase + o; o += 16384;
    float* lfA     = fbase + o; o += 16384;
    float* lfB     = fbase + o; o += 16384;
    float* xnsc_s  = fbase + o; o += 65536;
    float* xnsc_c  = fbase + o; o += 65536;
    float* xnraw_c = fbase + o; o += 65536;
    float* alog_s  = fbase + o; o += 65536;
    float* alog_c  = fbase + o; o += 65536;

    k_colnorm<<<dim3(128,2), 512, 0, stream>>>(Srep, Crep, scale_s, g_s, scale_c, g_c);
    k_rowstats<<<dim3(65536,2), 128, 0, stream>>>(Srep, Crep, scale_s, scale_c,
                                                  xnsc_s, xnsc_c, xnraw_c);
    k_mv_wl<<<65536, 128, 0, stream>>>(Crep, Wl, xnraw_c, g_s, A1g);
    k_L<<<65536, 512, 0, stream>>>(A1g, Srep, L_e);
    k_mv_w<<<65536, 128, 0, stream>>>(Srep, scale_s, xnsc_s, Ws, Hsa);
    e3_projrow<<<16384, 256, 0, stream>>>(Hsa, lfA);
    k_mv_w<<<65536, 128, 0, stream>>>(Crep, scale_c, xnsc_c, Wc, Hsb0);
    e3_projrow<<<16384, 256, 0, stream>>>(Hsb0, lfB);
    k_Hrow<0><<<dim3(128,128), 512, 0, stream>>>(Hsb0, lfB, L_e, Hsa, Hs_fin);
    k_Hrow<1><<<dim3(128,128), 512, 0, stream>>>(Hsa, lfA, L_e, Hsb0, Hc_fin);
    att2<<<128, 256, 0, stream>>>(Hs_fin, whs, alog_s, out + 25600);
    att2<<<128, 256, 0, stream>>>(Hc_fin, whc, alog_c, out + 25600 + 65536);
    co2<<<128, 256, 0, stream>>>(Srep, Crep, alog_s, alog_c, out);
    (void)in_sizes; (void)n_in; (void)ws_size;
}

// Round 11
// 1857.572 us; speedup vs baseline: 2.0192x; 2.0192x over previous
//
#include <hip/hip_runtime.h>
#include <hip/hip_bf16.h>
#include <math.h>

#define MINV 1e-15f
#define MAXN 0.996f   // (1 - 4e-3) / sqrt(c), c = 1

__device__ __forceinline__ float artanh_f(float x){
    x = fminf(fmaxf(x, -1.0f + 1e-7f), 1.0f - 1e-7f);
    return 0.5f * (log1pf(x) - log1pf(-x));
}

template<int NW>
__device__ __forceinline__ float block_sum(float v, float* sm){
    #pragma unroll
    for(int o=32;o>0;o>>=1) v += __shfl_down(v,o);
    int lane = threadIdx.x & 63, w = threadIdx.x >> 6;
    if(lane==0) sm[w] = v;
    __syncthreads();
    if(w==0){
        float t = (lane<NW)? sm[lane] : 0.0f;
        #pragma unroll
        for(int o=32;o>0;o>>=1) t += __shfl_down(t,o);
        if(lane==0) sm[0] = t;
    }
    __syncthreads();
    float r = sm[0];
    __syncthreads();
    return r;
}

// ---- LDS-tree reductions for 256-thread blocks ----
__device__ __forceinline__ float tree_sum256(float v, float* red){
    int tid = threadIdx.x;
    __syncthreads();
    red[tid] = v;
    __syncthreads();
    for(int o = 128; o > 0; o >>= 1){
        if(tid < o) red[tid] += red[tid + o];
        __syncthreads();
    }
    return red[0];
}
__device__ __forceinline__ float tree_max256(float v, float* red){
    int tid = threadIdx.x;
    __syncthreads();
    red[tid] = v;
    __syncthreads();
    for(int o = 128; o > 0; o >>= 1){
        if(tid < o) red[tid] = fmaxf(red[tid], red[tid + o]);
        __syncthreads();
    }
    return red[0];
}

// ---- per-(b,d) column stats over the 512 positions (s_t / c_t proj+logmap) ----
__global__ void k_colnorm(const float* __restrict__ Srep, const float* __restrict__ Crep,
                          float* scale_s, float* g_s, float* scale_c, float* g_c){
    int b = blockIdx.x;
    bool isC = (blockIdx.y == 1);
    const float* X = isC ? Crep : Srep;
    float* sc = isC ? scale_c : scale_s;
    float* gg = isC ? g_c : g_s;
    int d = threadIdx.x & 127, grp = threadIdx.x >> 7;
    float acc = 0.f;
    if(d < 100){
        const float* base = X + (size_t)b*512*100 + d;
        for(int s = grp; s < 512; s += 4){ float x = base[(size_t)s*100]; acc += x*x; }
    }
    __shared__ float sm[4][128];
    sm[grp][d] = acc;
    __syncthreads();
    if(grp == 0){
        if(d < 100){
            float tot = sm[0][d]+sm[1][d]+sm[2][d]+sm[3][d];
            float n1 = fmaxf(sqrtf(tot), MINV);
            float scale = (n1 > MAXN) ? MAXN/n1 : 1.0f;
            float pn = fminf(n1, MAXN);
            sc[b*128+d] = scale;
            gg[b*128+d] = artanh_f(pn)/pn * scale;
        } else {
            sc[b*128+d] = 0.f;
            gg[b*128+d] = 0.f;
        }
    }
}

// ---- per-row (over D=100) stats: scaled norm (for matvec) + raw norm (for Wl) ----
__global__ void k_rowstats(const float* __restrict__ Srep, const float* __restrict__ Crep,
                           const float* __restrict__ scale_s, const float* __restrict__ scale_c,
                           float* xnsc_s, float* xnsc_c, float* xnraw_c){
    int row = blockIdx.x;               // b*512 + s
    bool isC = (blockIdx.y == 1);
    const float* X = (isC ? Crep : Srep) + (size_t)row*100;
    const float* sc = (isC ? scale_c : scale_s) + (size_t)(row >> 9)*128;
    int d = threadIdx.x;
    float xr = 0.f, xs = 0.f;
    if(d < 100){ float v = X[d]; xr = v*v; float w = sc[d]*v; xs = w*w; }
    __shared__ float sm[2];
    float r2 = block_sum<2>(xr, sm);
    float s2 = block_sum<2>(xs, sm);
    if(threadIdx.x == 0){
        float nr = fmaxf(sqrtf(r2), MINV);
        float ns = fmaxf(sqrtf(s2), MINV);
        if(isC){ xnsc_c[row] = ns; xnraw_c[row] = nr; }
        else   { xnsc_s[row] = ns; }
    }
}

// ---- Wl matvec + mobius finalize + proj + logmap + fold g_s -> A1g [B,512,100] ----
__global__ void k_mv_wl(const float* __restrict__ Crep, const float* __restrict__ Wl,
                        const float* __restrict__ xnraw_c, const float* __restrict__ g_s,
                        float* __restrict__ A1g){
    int row = blockIdx.x;            // b*512 + t
    int b = row >> 9;
    __shared__ float xr[100];
    __shared__ float sm[2];
    int i = threadIdx.x;             // 0..127
    if(i < 100) xr[i] = Crep[(size_t)row*100 + i];
    __syncthreads();
    float mx = 0.f;
    if(i < 100){
        const float* w = Wl + (size_t)i*100;
        for(int d = 0; d < 100; d++) mx = fmaf(w[d], xr[d], mx);
    }
    float ss = block_sum<2>((i < 100) ? mx*mx : 0.f, sm);
    float mxn = fmaxf(sqrtf(ss), MINV);
    float xn = xnraw_c[row];
    float t1 = tanhf(mxn/xn * artanh_f(xn));
    float ps = (t1 > MAXN) ? MAXN/t1 : 1.0f;
    float m = fmaxf(fminf(t1, MAXN), MINV);
    float q = (t1/mxn) * ps * (artanh_f(m)/m);
    if(i < 100) A1g[(size_t)row*100 + i] = q * mx * g_s[b*128 + i];
}

// ---- Ws/Wc matvec on scaled rep + mobius finalize, write transposed [B,K,S] ----
__global__ void k_mv_w(const float* __restrict__ rep, const float* __restrict__ scale,
                       const float* __restrict__ xnsc, const float* __restrict__ W,
                       float* __restrict__ Out){
    int row = blockIdx.x;            // b*512 + s
    int b = row >> 9, s = row & 511;
    __shared__ float xr[100];
    __shared__ float sm[2];
    int k = threadIdx.x;             // 0..127
    if(k < 100) xr[k] = rep[(size_t)row*100 + k] * scale[b*128 + k];
    __syncthreads();
    float mx = 0.f;
    const float* w = W + (size_t)k*100;
    for(int d = 0; d < 100; d++) mx = fmaf(w[d], xr[d], mx);
    float ss = block_sum<2>(mx*mx, sm);
    float mxn = fmaxf(sqrtf(ss), MINV);
    float xn = xnsc[row];
    float t1 = tanhf(mxn/xn * artanh_f(xn));
    float mult = t1/mxn;
    Out[(size_t)b*65536 + (size_t)k*512 + s] = mx * mult;
}

// ---- proj rows (len 512) in place + store logmap factor ----
__global__ void e3_projrow(float* __restrict__ X, float* __restrict__ lf){
    int row = blockIdx.x;
    float* p = X + (size_t)row*512;
    int t = threadIdx.x;
    float v0 = p[t], v1 = p[t+256];
    __shared__ float sm[4];
    float ss = block_sum<4>(v0*v0 + v1*v1, sm);
    float n = fmaxf(sqrtf(ss), MINV);
    if(n > MAXN){ float ps = MAXN/n; p[t] = v0*ps; p[t+256] = v1*ps; }
    float m = fminf(n, MAXN);
    if(t == 0) lf[row] = artanh_f(m)/m;
}

// ---- tiled batched GEMM (validated in rounds 2/3 cross-check):
// C[b] = (msc .* A[b]) x B(^T).  BT: B is [N,Kc] vs [Kc,N].  BF16B: B bf16.
// TANHOUT: store bf16(tanh(acc)) else fp32 acc. ----
template<int BT, int BF16B, int TANHOUT>
__global__ __launch_bounds__(256) void gemm_t(
    const float* __restrict__ A, size_t aStr, int lda,
    const void* __restrict__ Bv, size_t bStr, int ldb,
    void* __restrict__ Cv, size_t cStr, int ldc,
    int M, int N, int Kc,
    const float* __restrict__ msc, int msStr)
{
    int bz = blockIdx.z;
    A += (size_t)bz*aStr;
    const float* Bf = (const float*)Bv + (BF16B ? 0 : (size_t)bz*bStr);
    const __hip_bfloat16* Bh = (const __hip_bfloat16*)Bv + (BF16B ? (size_t)bz*bStr : 0);
    const float* mscb = msc ? msc + (size_t)bz*msStr : nullptr;
    int m0 = blockIdx.x*128, n0 = blockIdx.y*128;
    __shared__ float As[32][132];
    __shared__ float Bs[32][132];
    float acc[8][8];
    #pragma unroll
    for(int i=0;i<8;i++)
        #pragma unroll
        for(int j=0;j<8;j++) acc[i][j] = 0.f;
    int tid = threadIdx.x;
    int ty = tid >> 4, tx = tid & 15;
    for(int k0 = 0; k0 < Kc; k0 += 32){
        for(int idx = tid; idx < 4096; idx += 256){
            int kc = idx & 31;
            int mm = idx >> 5;
            int gk = k0 + kc;
            int gm = m0 + mm;
            float v = 0.f;
            if(gk < Kc){
                v = A[(size_t)gm*lda + gk];
                if(mscb) v *= mscb[gm];
            }
            As[kc][mm] = v;
        }
        for(int idx = tid; idx < 4096; idx += 256){
            int kc, nn;
            if(BT){ kc = idx & 31; nn = idx >> 5; }
            else  { nn = idx & 127; kc = idx >> 7; }
            int gk = k0 + kc;
            int gn = n0 + nn;
            float v = 0.f;
            if(gk < Kc && gn < N){
                size_t off = BT ? ((size_t)gn*ldb + gk) : ((size_t)gk*ldb + gn);
                v = BF16B ? __bfloat162float(Bh[off]) : Bf[off];
            }
            Bs[kc][nn] = v;
        }
        __syncthreads();
        #pragma unroll 4
        for(int kc = 0; kc < 32; kc++){
            float a[8], b[8];
            *(float4*)&a[0] = *(const float4*)&As[kc][ty*8];
            *(float4*)&a[4] = *(const float4*)&As[kc][ty*8+4];
            *(float4*)&b[0] = *(const float4*)&Bs[kc][tx*8];
            *(float4*)&b[4] = *(const float4*)&Bs[kc][tx*8+4];
            #pragma unroll
            for(int i=0;i<8;i++)
                #pragma unroll
                for(int j=0;j<8;j++)
                    acc[i][j] = fmaf(a[i], b[j], acc[i][j]);
        }
        __syncthreads();
    }
    #pragma unroll
    for(int i=0;i<8;i++){
        int m = m0 + ty*8 + i;
        #pragma unroll
        for(int j=0;j<8;j++){
            int n = n0 + tx*8 + j;
            if(n < N){
                if(TANHOUT)
                    ((__hip_bfloat16*)Cv)[(size_t)bz*cStr + (size_t)m*ldc + n] = __float2bfloat16(tanhf(acc[i][j]));
                else
                    ((float*)Cv)[(size_t)bz*cStr + (size_t)m*ldc + n] = acc[i][j];
            }
        }
    }
}

// ---- L epilogue on bf16 tanh(L) rows: scale by artanh(min(tanh(un),MAXN))/un ----
__global__ void e_modeL_b16(__hip_bfloat16* __restrict__ X){
    int row = blockIdx.x;
    __hip_bfloat16* p = X + (size_t)row*512;
    int t = threadIdx.x;
    float v0 = __bfloat162float(p[t]);
    float v1 = __bfloat162float(p[t+256]);
    __shared__ float sm[4];
    float ss = block_sum<4>(v0*v0 + v1*v1, sm);
    float un = fmaxf(sqrtf(ss), MINV);
    float pn = fminf(tanhf(un), MAXN);
    float f = artanh_f(pn)/un;
    p[t] = __float2bfloat16(f*v0);
    p[t+256] = __float2bfloat16(f*v1);
}

// ---- H epilogue chain (k_Hrow tail, validated): y=expmap0+proj(Y-row);
//      mobius_add(x=X-row, y); proj; logmap0; tanh; expmap0; proj -> in-place Y ----
__global__ void e_chain(float* __restrict__ Y, const float* __restrict__ X){
    int row = blockIdx.x;               // b*128 + k
    __shared__ float sm[8];
    int t = threadIdx.x;                // 0..511
    size_t rowoff = (size_t)row*512;
    float acc = Y[rowoff + t];
    float ss = block_sum<8>(acc*acc, sm);
    float un = fmaxf(sqrtf(ss), MINV);
    float y = fminf(tanhf(un), MAXN)/un * acc;
    float x = X[rowoff + t];
    float x2 = block_sum<8>(x*x, sm);
    float y2 = block_sum<8>(y*y, sm);
    float xy = block_sum<8>(x*y, sm);
    float a  = 1.f + 2.f*xy + y2;
    float bb = 1.f - x2;
    float den = fmaxf(1.f + 2.f*xy + x2*y2, MINV);
    float z = (a*x + bb*y)/den;
    float zz = block_sum<8>(z*z, sm);
    float n = fmaxf(sqrtf(zz), MINV);
    float ps = (n > MAXN) ? MAXN/n : 1.f;
    float mm = fminf(n, MAXN);
    float lf2 = artanh_f(mm)/mm * ps;
    float v = tanhf(lf2*z);
    float vv = block_sum<8>(v*v, sm);
    float un2 = fmaxf(sqrtf(vv), MINV);
    float f2 = fminf(tanhf(un2), MAXN)/un2;
    Y[rowoff + t] = f2*v;
}

// ---- attention: wh-matvec + proj + logmap + softmax + expmap + proj (f32 out) ----
__global__ void att2(const float* __restrict__ H, const float* __restrict__ wh,
                     float* __restrict__ alog, float* __restrict__ outAtt){
    int b = blockIdx.x;
    int tid = threadIdx.x;              // 0..255
    __shared__ float whl[128];
    __shared__ float red[256];
    if(tid < 128) whl[tid] = wh[tid];
    __syncthreads();
    float res2[2];
    #pragma unroll
    for(int h = 0; h < 2; h++){
        int s = tid + h*256;
        const float* hp = H + (size_t)b*65536 + s;
        float mx = 0.f, x2 = 0.f;
        for(int k = 0; k < 128; k++){
            float v = hp[(size_t)k*512];
            mx = fmaf(whl[k], v, mx);
            x2 = fmaf(v, v, x2);
        }
        float xn  = fmaxf(sqrtf(x2), MINV);
        float mxn = fmaxf(fabsf(mx), MINV);
        float t1 = tanhf(mxn/xn * artanh_f(xn));
        res2[h] = t1 * (mx/mxn);
    }
    float rr = tree_sum256(res2[0]*res2[0] + res2[1]*res2[1], red);
    float n = fmaxf(sqrtf(rr), MINV);
    float ps = (n > MAXN) ? MAXN/n : 1.f;
    float m = fminf(n, MAXN);
    float lfw = artanh_f(m)/m * ps;
    float w0 = lfw*res2[0], w1 = lfw*res2[1];
    float wmax = tree_max256(fmaxf(w0, w1), red);
    float e0 = expf(w0 - wmax), e1 = expf(w1 - wmax);
    float es = tree_sum256(e0 + e1, red);
    float p0 = e0/es, p1 = e1/es;
    float pp = tree_sum256(p0*p0 + p1*p1, red);
    float un = fmaxf(sqrtf(pp), MINV);
    float th = tanhf(un);
    float f = fminf(th, MAXN)/un;
    float A0 = f*p0, A1 = f*p1;
    outAtt[b*512 + tid]       = A0;
    outAtt[b*512 + tid + 256] = A1;
    float m2 = fmaxf(fminf(th, MAXN), MINV);
    float fl = artanh_f(m2)/m2;
    alog[b*512 + tid]       = fl*A0;
    alog[b*512 + tid + 256] = fl*A1;
}

// ---- co kernel: both co_s and co_c; recomputes logmap0(rep) factors inline ----
__global__ void co2(const float* __restrict__ Srep, const float* __restrict__ Crep,
                    const float* __restrict__ alog_s, const float* __restrict__ alog_c,
                    float* __restrict__ out){
    int b = blockIdx.x, tid = threadIdx.x;   // 256 threads
    __shared__ float ws_[512], wc_[512];
    #pragma unroll
    for(int h = 0; h < 2; h++){
        int s = tid + h*256;
        const float* sp = Srep + (size_t)(b*512 + s)*100;
        const float* cp = Crep + (size_t)(b*512 + s)*100;
        float s2 = 0.f, c2 = 0.f;
        for(int d = 0; d < 100; d++){
            float a = sp[d]; s2 = fmaf(a, a, s2);
            float e = cp[d]; c2 = fmaf(e, e, c2);
        }
        float nsr = fmaxf(sqrtf(s2), MINV);
        float ncr = fmaxf(sqrtf(c2), MINV);
        ws_[s] = alog_s[b*512 + s] * (artanh_f(nsr)/nsr);
        wc_[s] = alog_c[b*512 + s] * (artanh_f(ncr)/ncr);
    }
    __syncthreads();
    if(tid < 100){
        float acc = 0.f;
        const float* rp = Srep + (size_t)b*51200 + tid;
        for(int s = 0; s < 512; s++) acc = fmaf(ws_[s], rp[(size_t)s*100], acc);
        out[b*200 + tid] = acc;
    } else if(tid >= 128 && tid < 228){
        int d = tid - 128;
        float acc = 0.f;
        const float* rp = Crep + (size_t)b*51200 + d;
        for(int s = 0; s < 512; s++) acc = fmaf(wc_[s], rp[(size_t)s*100], acc);
        out[b*200 + 100 + d] = acc;
    }
}

// ---- diagnostic fill (f32) ----
__global__ void k_fill(float* out, int n, float v){
    int i = blockIdx.x*256 + threadIdx.x;
    if(i < n) out[i] = v;
}

extern "C" void kernel_launch(void* const* d_in, const int* in_sizes, int n_in,
                              void* d_out, int out_size, void* d_ws, size_t ws_size,
                              hipStream_t stream)
{
    const float* Srep = (const float*)d_in[0];   // sentence_rep
    const float* Crep = (const float*)d_in[1];   // comment_rep
    const float* Wl   = (const float*)d_in[2];
    const float* Wc   = (const float*)d_in[3];
    const float* Ws   = (const float*)d_in[4];
    const float* whs  = (const float*)d_in[5];
    const float* whc  = (const float*)d_in[6];
    float* out = (float*)d_out;                  // fp32 output (round-9 finding)

    bool ok = (n_in == 7) &&
              in_sizes[0] == 6553600 && in_sizes[1] == 6553600 &&
              in_sizes[2] == 10000   && in_sizes[3] == 12800 &&
              in_sizes[4] == 12800   && in_sizes[5] == 128 && in_sizes[6] == 128 &&
              out_size == 156672;
    if(!ok){
        k_fill<<<(out_size+255)/256, 256, 0, stream>>>(out, out_size, 1.0f);
        return;
    }

    const size_t L_E_BYTES  = (size_t)128*512*512*2;     // 67.1 MB bf16
    const size_t A1G_ELTS   = (size_t)128*512*100;
    const size_t HBUF_ELTS  = (size_t)128*128*512;
    const size_t SMALL_ELTS = 6*16384 + 7*65536;
    const size_t REQ = L_E_BYTES + (A1G_ELTS + 4*HBUF_ELTS + SMALL_ELTS)*4;  // ~230 MB
    if(ws_size < REQ){
        k_fill<<<(out_size+255)/256, 256, 0, stream>>>(out, out_size, -1.0f);
        return;
    }

    char* base = (char*)d_ws;
    __hip_bfloat16* L_e = (__hip_bfloat16*)base;
    float* fbase = (float*)(base + L_E_BYTES);
    size_t o = 0;
    float* A1g    = fbase + o; o += A1G_ELTS;
    float* Hsa    = fbase + o; o += HBUF_ELTS;   // Hs_a (chain for Hs; log-src for Hc_b)
    float* Hsb0   = fbase + o; o += HBUF_ELTS;   // Hc_a (chain for Hc; log-src for Hs_b)
    float* Ys     = fbase + o; o += HBUF_ELTS;   // GEMM2 out -> e_chain in-place -> Hs
    float* Yc     = fbase + o; o += HBUF_ELTS;   // GEMM3 out -> e_chain in-place -> Hc
    float* scale_s = fbase + o; o += 16384;
    float* g_s     = fbase + o; o += 16384;
    float* scale_c = fbase + o; o += 16384;
    float* g_c     = fbase + o; o += 16384;
    float* lfA     = fbase + o; o += 16384;
    float* lfB     = fbase + o; o += 16384;
    float* xnsc_s  = fbase + o; o += 65536;
    float* xnsc_c  = fbase + o; o += 65536;
    float* xnraw_c = fbase + o; o += 65536;
    float* alog_s  = fbase + o; o += 65536;
    float* alog_c  = fbase + o; o += 65536;

    // stats
    k_colnorm<<<dim3(128,2), 512, 0, stream>>>(Srep, Crep, scale_s, g_s, scale_c, g_c);
    k_rowstats<<<dim3(65536,2), 128, 0, stream>>>(Srep, Crep, scale_s, scale_c,
                                                  xnsc_s, xnsc_c, xnraw_c);
    // A1g = logmap0(proj(mobius_matvec(Wl, comment_rep))) .* g_s   [B,512,100]
    k_mv_wl<<<65536, 128, 0, stream>>>(Crep, Wl, xnraw_c, g_s, A1g);
    // GEMM1: L_t(bf16) = tanh(A1g @ Srep^T), then row rescale -> L_e
    gemm_t<1,0,1><<<dim3(4,4,128), 256, 0, stream>>>(A1g, (size_t)512*100, 100,
                                                     Srep, (size_t)512*100, 100,
                                                     L_e, (size_t)512*512, 512,
                                                     512, 512, 100, nullptr, 0);
    e_modeL_b16<<<65536, 256, 0, stream>>>(L_e);
    // Hs_a / Hc_a bases (transposed [B,K,512]) + proj + logmap factors
    k_mv_w<<<65536, 128, 0, stream>>>(Srep, scale_s, xnsc_s, Ws, Hsa);
    e3_projrow<<<16384, 256, 0, stream>>>(Hsa, lfA);
    k_mv_w<<<65536, 128, 0, stream>>>(Crep, scale_c, xnsc_c, Wc, Hsb0);
    e3_projrow<<<16384, 256, 0, stream>>>(Hsb0, lfB);
    // GEMM2 (NN, bf16 B): Ys = (lfB.*Hsb0) @ L_e
    gemm_t<0,1,0><<<dim3(1,4,128), 256, 0, stream>>>(Hsb0, (size_t)128*512, 512,
                                                     L_e, (size_t)512*512, 512,
                                                     Ys, (size_t)128*512, 512,
                                                     128, 512, 512, lfB, 128);
    // GEMM3 (NT, bf16 B): Yc = (lfA.*Hsa) @ L_e^T
    gemm_t<1,1,0><<<dim3(1,4,128), 256, 0, stream>>>(Hsa, (size_t)128*512, 512,
                                                     L_e, (size_t)512*512, 512,
                                                     Yc, (size_t)128*512, 512,
                                                     128, 512, 512, lfA, 128);
    // H chains (in-place): Hs = chain(Hsa, Ys); Hc = chain(Hsb0, Yc)
    e_chain<<<16384, 512, 0, stream>>>(Ys, Hsa);
    e_chain<<<16384, 512, 0, stream>>>(Yc, Hsb0);
    // attentions + outputs
    att2<<<128, 256, 0, stream>>>(Ys, whs, alog_s, out + 25600);
    att2<<<128, 256, 0, stream>>>(Yc, whc, alog_c, out + 25600 + 65536);
    co2<<<128, 256, 0, stream>>>(Srep, Crep, alog_s, alog_c, out);
    (void)in_sizes; (void)n_in; (void)ws_size;
}

// Round 12
// 1246.834 us; speedup vs baseline: 3.0083x; 1.4898x over previous
//
#include <hip/hip_runtime.h>
#include <hip/hip_bf16.h>
#include <math.h>

#define MINV 1e-15f
#define MAXN 0.996f   // (1 - 4e-3) / sqrt(c), c = 1

__device__ __forceinline__ float artanh_f(float x){
    x = fminf(fmaxf(x, -1.0f + 1e-7f), 1.0f - 1e-7f);
    return 0.5f * (log1pf(x) - log1pf(-x));
}

template<int NW>
__device__ __forceinline__ float block_sum(float v, float* sm){
    #pragma unroll
    for(int o=32;o>0;o>>=1) v += __shfl_down(v,o);
    int lane = threadIdx.x & 63, w = threadIdx.x >> 6;
    if(lane==0) sm[w] = v;
    __syncthreads();
    if(w==0){
        float t = (lane<NW)? sm[lane] : 0.0f;
        #pragma unroll
        for(int o=32;o>0;o>>=1) t += __shfl_down(t,o);
        if(lane==0) sm[0] = t;
    }
    __syncthreads();
    float r = sm[0];
    __syncthreads();
    return r;
}

// ---- LDS-tree reductions for 256-thread blocks ----
__device__ __forceinline__ float tree_sum256(float v, float* red){
    int tid = threadIdx.x;
    __syncthreads();
    red[tid] = v;
    __syncthreads();
    for(int o = 128; o > 0; o >>= 1){
        if(tid < o) red[tid] += red[tid + o];
        __syncthreads();
    }
    return red[0];
}
__device__ __forceinline__ float tree_max256(float v, float* red){
    int tid = threadIdx.x;
    __syncthreads();
    red[tid] = v;
    __syncthreads();
    for(int o = 128; o > 0; o >>= 1){
        if(tid < o) red[tid] = fmaxf(red[tid], red[tid + o]);
        __syncthreads();
    }
    return red[0];
}

// ---- per-(b,d) column stats over the 512 positions (s_t / c_t proj+logmap) ----
__global__ void k_colnorm(const float* __restrict__ Srep, const float* __restrict__ Crep,
                          float* scale_s, float* g_s, float* scale_c, float* g_c){
    int b = blockIdx.x;
    bool isC = (blockIdx.y == 1);
    const float* X = isC ? Crep : Srep;
    float* sc = isC ? scale_c : scale_s;
    float* gg = isC ? g_c : g_s;
    int d = threadIdx.x & 127, grp = threadIdx.x >> 7;
    float acc = 0.f;
    if(d < 100){
        const float* base = X + (size_t)b*512*100 + d;
        for(int s = grp; s < 512; s += 4){ float x = base[(size_t)s*100]; acc += x*x; }
    }
    __shared__ float sm[4][128];
    sm[grp][d] = acc;
    __syncthreads();
    if(grp == 0){
        if(d < 100){
            float tot = sm[0][d]+sm[1][d]+sm[2][d]+sm[3][d];
            float n1 = fmaxf(sqrtf(tot), MINV);
            float scale = (n1 > MAXN) ? MAXN/n1 : 1.0f;
            float pn = fminf(n1, MAXN);
            sc[b*128+d] = scale;
            gg[b*128+d] = artanh_f(pn)/pn * scale;
        } else {
            sc[b*128+d] = 0.f;
            gg[b*128+d] = 0.f;
        }
    }
}

// ---- per-row (over D=100) stats: scaled norm (for matvec) + raw norm (for Wl) ----
__global__ void k_rowstats(const float* __restrict__ Srep, const float* __restrict__ Crep,
                           const float* __restrict__ scale_s, const float* __restrict__ scale_c,
                           float* xnsc_s, float* xnsc_c, float* xnraw_c){
    int row = blockIdx.x;               // b*512 + s
    bool isC = (blockIdx.y == 1);
    const float* X = (isC ? Crep : Srep) + (size_t)row*100;
    const float* sc = (isC ? scale_c : scale_s) + (size_t)(row >> 9)*128;
    int d = threadIdx.x;
    float xr = 0.f, xs = 0.f;
    if(d < 100){ float v = X[d]; xr = v*v; float w = sc[d]*v; xs = w*w; }
    __shared__ float sm[2];
    float r2 = block_sum<2>(xr, sm);
    float s2 = block_sum<2>(xs, sm);
    if(threadIdx.x == 0){
        float nr = fmaxf(sqrtf(r2), MINV);
        float ns = fmaxf(sqrtf(s2), MINV);
        if(isC){ xnsc_c[row] = ns; xnraw_c[row] = nr; }
        else   { xnsc_s[row] = ns; }
    }
}

// ---- Wl matvec + mobius finalize + proj + logmap + fold g_s -> A1g [B,512,100] ----
__global__ void k_mv_wl(const float* __restrict__ Crep, const float* __restrict__ Wl,
                        const float* __restrict__ xnraw_c, const float* __restrict__ g_s,
                        float* __restrict__ A1g){
    int row = blockIdx.x;            // b*512 + t
    int b = row >> 9;
    __shared__ float xr[100];
    __shared__ float sm[2];
    int i = threadIdx.x;             // 0..127
    if(i < 100) xr[i] = Crep[(size_t)row*100 + i];
    __syncthreads();
    float mx = 0.f;
    if(i < 100){
        const float* w = Wl + (size_t)i*100;
        for(int d = 0; d < 100; d++) mx = fmaf(w[d], xr[d], mx);
    }
    float ss = block_sum<2>((i < 100) ? mx*mx : 0.f, sm);
    float mxn = fmaxf(sqrtf(ss), MINV);
    float xn = xnraw_c[row];
    float t1 = tanhf(mxn/xn * artanh_f(xn));
    float ps = (t1 > MAXN) ? MAXN/t1 : 1.0f;
    float m = fmaxf(fminf(t1, MAXN), MINV);
    float q = (t1/mxn) * ps * (artanh_f(m)/m);
    if(i < 100) A1g[(size_t)row*100 + i] = q * mx * g_s[b*128 + i];
}

// ---- proj rows (len 512) in place + store logmap factor ----
__global__ void e3_projrow(float* __restrict__ X, float* __restrict__ lf){
    int row = blockIdx.x;
    float* p = X + (size_t)row*512;
    int t = threadIdx.x;
    float v0 = p[t], v1 = p[t+256];
    __shared__ float sm[4];
    float ss = block_sum<4>(v0*v0 + v1*v1, sm);
    float n = fmaxf(sqrtf(ss), MINV);
    if(n > MAXN){ float ps = MAXN/n; p[t] = v0*ps; p[t+256] = v1*ps; }
    float m = fminf(n, MAXN);
    if(t == 0) lf[row] = artanh_f(m)/m;
}

// ---- tiled batched GEMM (validated): C[b] = (msc .* A[b]) x B(^T) ----
template<int BT, int BF16B, int TANHOUT>
__global__ __launch_bounds__(256) void gemm_t(
    const float* __restrict__ A, size_t aStr, int lda,
    const void* __restrict__ Bv, size_t bStr, int ldb,
    void* __restrict__ Cv, size_t cStr, int ldc,
    int M, int N, int Kc,
    const float* __restrict__ msc, int msStr)
{
    int bz = blockIdx.z;
    A += (size_t)bz*aStr;
    const float* Bf = (const float*)Bv + (BF16B ? 0 : (size_t)bz*bStr);
    const __hip_bfloat16* Bh = (const __hip_bfloat16*)Bv + (BF16B ? (size_t)bz*bStr : 0);
    const float* mscb = msc ? msc + (size_t)bz*msStr : nullptr;
    int m0 = blockIdx.x*128, n0 = blockIdx.y*128;
    __shared__ float As[32][132];
    __shared__ float Bs[32][132];
    float acc[8][8];
    #pragma unroll
    for(int i=0;i<8;i++)
        #pragma unroll
        for(int j=0;j<8;j++) acc[i][j] = 0.f;
    int tid = threadIdx.x;
    int ty = tid >> 4, tx = tid & 15;
    for(int k0 = 0; k0 < Kc; k0 += 32){
        for(int idx = tid; idx < 4096; idx += 256){
            int kc = idx & 31;
            int mm = idx >> 5;
            int gk = k0 + kc;
            int gm = m0 + mm;
            float v = 0.f;
            if(gk < Kc){
                v = A[(size_t)gm*lda + gk];
                if(mscb) v *= mscb[gm];
            }
            As[kc][mm] = v;
        }
        for(int idx = tid; idx < 4096; idx += 256){
            int kc, nn;
            if(BT){ kc = idx & 31; nn = idx >> 5; }
            else  { nn = idx & 127; kc = idx >> 7; }
            int gk = k0 + kc;
            int gn = n0 + nn;
            float v = 0.f;
            if(gk < Kc && gn < N){
                size_t off = BT ? ((size_t)gn*ldb + gk) : ((size_t)gk*ldb + gn);
                v = BF16B ? __bfloat162float(Bh[off]) : Bf[off];
            }
            Bs[kc][nn] = v;
        }
        __syncthreads();
        #pragma unroll 4
        for(int kc = 0; kc < 32; kc++){
            float a[8], b[8];
            *(float4*)&a[0] = *(const float4*)&As[kc][ty*8];
            *(float4*)&a[4] = *(const float4*)&As[kc][ty*8+4];
            *(float4*)&b[0] = *(const float4*)&Bs[kc][tx*8];
            *(float4*)&b[4] = *(const float4*)&Bs[kc][tx*8+4];
            #pragma unroll
            for(int i=0;i<8;i++)
                #pragma unroll
                for(int j=0;j<8;j++)
                    acc[i][j] = fmaf(a[i], b[j], acc[i][j]);
        }
        __syncthreads();
    }
    #pragma unroll
    for(int i=0;i<8;i++){
        int m = m0 + ty*8 + i;
        #pragma unroll
        for(int j=0;j<8;j++){
            int n = n0 + tx*8 + j;
            if(n < N){
                if(TANHOUT)
                    ((__hip_bfloat16*)Cv)[(size_t)bz*cStr + (size_t)m*ldc + n] = __float2bfloat16(tanhf(acc[i][j]));
                else
                    ((float*)Cv)[(size_t)bz*cStr + (size_t)m*ldc + n] = acc[i][j];
            }
        }
    }
}

// ---- mobius_matvec(W, scaled rep) fused: GEMM (M=512 s, N=128 k, K=100)
//      + per-s norm over k (shfl over the 16 lanes holding one row)
//      + t1/mxn scaling + LDS-transposed COALESCED write to [B,K,S].
//      blockIdx.y in [0,256): <128 -> sentence, >=128 -> comment. ----
__global__ __launch_bounds__(256) void gemm_mvw(
    const float* __restrict__ SrepG, const float* __restrict__ CrepG,
    const float* __restrict__ scale_s, const float* __restrict__ scale_c,
    const float* __restrict__ xnsc_s, const float* __restrict__ xnsc_c,
    const float* __restrict__ Ws, const float* __restrict__ Wc,
    float* __restrict__ OutS, float* __restrict__ OutC)
{
    int zz = blockIdx.y;
    int isC = (zz >= 128);
    int b = isC ? zz - 128 : zz;
    const float* A  = (isC ? CrepG : SrepG) + (size_t)b*51200;
    const float* sc = (isC ? scale_c : scale_s) + (size_t)b*128;
    const float* xn = (isC ? xnsc_c : xnsc_s) + (size_t)b*512;
    const float* W  = isC ? Wc : Ws;
    float* Out = (isC ? OutC : OutS) + (size_t)b*65536;
    int m0 = blockIdx.x*128;
    __shared__ float As[32][132];
    __shared__ float Bs[32][132];
    float acc[8][8];
    #pragma unroll
    for(int i=0;i<8;i++)
        #pragma unroll
        for(int j=0;j<8;j++) acc[i][j] = 0.f;
    int tid = threadIdx.x;
    int ty = tid >> 4, tx = tid & 15;
    for(int k0 = 0; k0 < 100; k0 += 32){
        for(int idx = tid; idx < 4096; idx += 256){
            int kc = idx & 31;
            int mm = idx >> 5;
            int gk = k0 + kc;
            float v = 0.f;
            if(gk < 100) v = A[(size_t)(m0+mm)*100 + gk] * sc[gk];
            As[kc][mm] = v;
        }
        for(int idx = tid; idx < 4096; idx += 256){
            int kc = idx & 31;
            int nn = idx >> 5;
            int gk = k0 + kc;
            float v = 0.f;
            if(gk < 100) v = W[(size_t)nn*100 + gk];
            Bs[kc][nn] = v;
        }
        __syncthreads();
        #pragma unroll 4
        for(int kc = 0; kc < 32; kc++){
            float a[8], bb[8];
            *(float4*)&a[0] = *(const float4*)&As[kc][ty*8];
            *(float4*)&a[4] = *(const float4*)&As[kc][ty*8+4];
            *(float4*)&bb[0] = *(const float4*)&Bs[kc][tx*8];
            *(float4*)&bb[4] = *(const float4*)&Bs[kc][tx*8+4];
            #pragma unroll
            for(int i=0;i<8;i++)
                #pragma unroll
                for(int j=0;j<8;j++)
                    acc[i][j] = fmaf(a[i], bb[j], acc[i][j]);
        }
        __syncthreads();
    }
    // per-s norm over the 128 k values (held by 16 lanes tx=0..15 of same ty)
    float mult[8];
    #pragma unroll
    for(int i=0;i<8;i++){
        float ps = 0.f;
        #pragma unroll
        for(int j=0;j<8;j++) ps = fmaf(acc[i][j], acc[i][j], ps);
        ps += __shfl_xor(ps, 1);
        ps += __shfl_xor(ps, 2);
        ps += __shfl_xor(ps, 4);
        ps += __shfl_xor(ps, 8);
        float mxn = fmaxf(sqrtf(ps), MINV);
        float x = xn[m0 + ty*8 + i];
        float t1 = tanhf(mxn/x * artanh_f(x));
        mult[i] = t1/mxn;
    }
    // transposed write: 4 chunks of 32 k-rows x 128 s, staged via Bs
    for(int c = 0; c < 4; c++){
        __syncthreads();
        if((tx >> 2) == c){
            #pragma unroll
            for(int j=0;j<8;j++)
                #pragma unroll
                for(int i=0;i<8;i++)
                    Bs[(tx&3)*8 + j][ty*8 + i] = acc[i][j]*mult[i];
        }
        __syncthreads();
        for(int w = tid; w < 4096; w += 256){
            int kr = w >> 7, sl = w & 127;
            Out[(size_t)(c*32 + kr)*512 + m0 + sl] = Bs[kr][sl];
        }
    }
}

// ---- merged H GEMMs: z<128 -> Ys = (lfB.*Hsb0[b]) @ L_e[b]      (NN)
//                      z>=128 -> Yc = (lfA.*Hsa[b]) @ L_e[b]^T    (NT) ----
__global__ __launch_bounds__(256) void gemm_h(
    const float* __restrict__ Hsa, const float* __restrict__ Hsb0,
    const float* __restrict__ lfA, const float* __restrict__ lfB,
    const __hip_bfloat16* __restrict__ L_e,
    float* __restrict__ Ys, float* __restrict__ Yc)
{
    int zz = blockIdx.z;
    int BT = (zz >= 128);
    int b = BT ? zz - 128 : zz;
    const float* A = (BT ? Hsa : Hsb0) + (size_t)b*65536;
    const float* msc = (BT ? lfA : lfB) + (size_t)b*128;
    const __hip_bfloat16* Bh = L_e + (size_t)b*262144;
    float* C = (BT ? Yc : Ys) + (size_t)b*65536;
    int n0 = blockIdx.y*128;         // m0 = 0 (M=128)
    __shared__ float As[32][132];
    __shared__ float Bs[32][132];
    float acc[8][8];
    #pragma unroll
    for(int i=0;i<8;i++)
        #pragma unroll
        for(int j=0;j<8;j++) acc[i][j] = 0.f;
    int tid = threadIdx.x;
    int ty = tid >> 4, tx = tid & 15;
    for(int k0 = 0; k0 < 512; k0 += 32){
        for(int idx = tid; idx < 4096; idx += 256){
            int kc = idx & 31;
            int mm = idx >> 5;
            int gk = k0 + kc;
            As[kc][mm] = A[(size_t)mm*512 + gk] * msc[mm];
        }
        for(int idx = tid; idx < 4096; idx += 256){
            int kc, nn;
            if(BT){ kc = idx & 31; nn = idx >> 5; }
            else  { nn = idx & 127; kc = idx >> 7; }
            int gk = k0 + kc;
            int gn = n0 + nn;
            size_t off = BT ? ((size_t)gn*512 + gk) : ((size_t)gk*512 + gn);
            Bs[kc][nn] = __bfloat162float(Bh[off]);
        }
        __syncthreads();
        #pragma unroll 4
        for(int kc = 0; kc < 32; kc++){
            float a[8], bb[8];
            *(float4*)&a[0] = *(const float4*)&As[kc][ty*8];
            *(float4*)&a[4] = *(const float4*)&As[kc][ty*8+4];
            *(float4*)&bb[0] = *(const float4*)&Bs[kc][tx*8];
            *(float4*)&bb[4] = *(const float4*)&Bs[kc][tx*8+4];
            #pragma unroll
            for(int i=0;i<8;i++)
                #pragma unroll
                for(int j=0;j<8;j++)
                    acc[i][j] = fmaf(a[i], bb[j], acc[i][j]);
        }
        __syncthreads();
    }
    #pragma unroll
    for(int i=0;i<8;i++){
        int m = ty*8 + i;
        #pragma unroll
        for(int j=0;j<8;j++){
            int n = n0 + tx*8 + j;
            C[(size_t)m*512 + n] = acc[i][j];
        }
    }
}

// ---- L epilogue on bf16 tanh(L) rows: scale by artanh(min(tanh(un),MAXN))/un ----
__global__ void e_modeL_b16(__hip_bfloat16* __restrict__ X){
    int row = blockIdx.x;
    __hip_bfloat16* p = X + (size_t)row*512;
    int t = threadIdx.x;
    float v0 = __bfloat162float(p[t]);
    float v1 = __bfloat162float(p[t+256]);
    __shared__ float sm[4];
    float ss = block_sum<4>(v0*v0 + v1*v1, sm);
    float un = fmaxf(sqrtf(ss), MINV);
    float pn = fminf(tanhf(un), MAXN);
    float f = artanh_f(pn)/un;
    p[t] = __float2bfloat16(f*v0);
    p[t+256] = __float2bfloat16(f*v1);
}

// ---- H epilogue chain: y=expmap0+proj(Y); mobius_add(X,y); proj; logmap0;
//      tanh; expmap0; proj -> in-place Y ----
__global__ void e_chain(float* __restrict__ Y, const float* __restrict__ X){
    int row = blockIdx.x;               // b*128 + k
    __shared__ float sm[8];
    int t = threadIdx.x;                // 0..511
    size_t rowoff = (size_t)row*512;
    float acc = Y[rowoff + t];
    float ss = block_sum<8>(acc*acc, sm);
    float un = fmaxf(sqrtf(ss), MINV);
    float y = fminf(tanhf(un), MAXN)/un * acc;
    float x = X[rowoff + t];
    float x2 = block_sum<8>(x*x, sm);
    float y2 = block_sum<8>(y*y, sm);
    float xy = block_sum<8>(x*y, sm);
    float a  = 1.f + 2.f*xy + y2;
    float bb = 1.f - x2;
    float den = fmaxf(1.f + 2.f*xy + x2*y2, MINV);
    float z = (a*x + bb*y)/den;
    float zz = block_sum<8>(z*z, sm);
    float n = fmaxf(sqrtf(zz), MINV);
    float ps = (n > MAXN) ? MAXN/n : 1.f;
    float mm = fminf(n, MAXN);
    float lf2 = artanh_f(mm)/mm * ps;
    float v = tanhf(lf2*z);
    float vv = block_sum<8>(v*v, sm);
    float un2 = fmaxf(sqrtf(vv), MINV);
    float f2 = fminf(tanhf(un2), MAXN)/un2;
    Y[rowoff + t] = f2*v;
}

// ---- attention: wh-matvec + proj + logmap + softmax + expmap + proj (f32 out) ----
__global__ void att2(const float* __restrict__ H, const float* __restrict__ wh,
                     float* __restrict__ alog, float* __restrict__ outAtt){
    int b = blockIdx.x;
    int tid = threadIdx.x;              // 0..255
    __shared__ float whl[128];
    __shared__ float red[256];
    if(tid < 128) whl[tid] = wh[tid];
    __syncthreads();
    float res2[2];
    #pragma unroll
    for(int h = 0; h < 2; h++){
        int s = tid + h*256;
        const float* hp = H + (size_t)b*65536 + s;
        float mx = 0.f, x2 = 0.f;
        for(int k = 0; k < 128; k++){
            float v = hp[(size_t)k*512];
            mx = fmaf(whl[k], v, mx);
            x2 = fmaf(v, v, x2);
        }
        float xn  = fmaxf(sqrtf(x2), MINV);
        float mxn = fmaxf(fabsf(mx), MINV);
        float t1 = tanhf(mxn/xn * artanh_f(xn));
        res2[h] = t1 * (mx/mxn);
    }
    float rr = tree_sum256(res2[0]*res2[0] + res2[1]*res2[1], red);
    float n = fmaxf(sqrtf(rr), MINV);
    float ps = (n > MAXN) ? MAXN/n : 1.f;
    float m = fminf(n, MAXN);
    float lfw = artanh_f(m)/m * ps;
    float w0 = lfw*res2[0], w1 = lfw*res2[1];
    float wmax = tree_max256(fmaxf(w0, w1), red);
    float e0 = expf(w0 - wmax), e1 = expf(w1 - wmax);
    float es = tree_sum256(e0 + e1, red);
    float p0 = e0/es, p1 = e1/es;
    float pp = tree_sum256(p0*p0 + p1*p1, red);
    float un = fmaxf(sqrtf(pp), MINV);
    float th = tanhf(un);
    float f = fminf(th, MAXN)/un;
    float A0 = f*p0, A1 = f*p1;
    outAtt[b*512 + tid]       = A0;
    outAtt[b*512 + tid + 256] = A1;
    float m2 = fmaxf(fminf(th, MAXN), MINV);
    float fl = artanh_f(m2)/m2;
    alog[b*512 + tid]       = fl*A0;
    alog[b*512 + tid + 256] = fl*A1;
}

// ---- co kernel: both co_s and co_c; recomputes logmap0(rep) factors inline ----
__global__ void co2(const float* __restrict__ Srep, const float* __restrict__ Crep,
                    const float* __restrict__ alog_s, const float* __restrict__ alog_c,
                    float* __restrict__ out){
    int b = blockIdx.x, tid = threadIdx.x;   // 256 threads
    __shared__ float ws_[512], wc_[512];
    #pragma unroll
    for(int h = 0; h < 2; h++){
        int s = tid + h*256;
        const float* sp = Srep + (size_t)(b*512 + s)*100;
        const float* cp = Crep + (size_t)(b*512 + s)*100;
        float s2 = 0.f, c2 = 0.f;
        for(int d = 0; d < 100; d++){
            float a = sp[d]; s2 = fmaf(a, a, s2);
            float e = cp[d]; c2 = fmaf(e, e, c2);
        }
        float nsr = fmaxf(sqrtf(s2), MINV);
        float ncr = fmaxf(sqrtf(c2), MINV);
        ws_[s] = alog_s[b*512 + s] * (artanh_f(nsr)/nsr);
        wc_[s] = alog_c[b*512 + s] * (artanh_f(ncr)/ncr);
    }
    __syncthreads();
    if(tid < 100){
        float acc = 0.f;
        const float* rp = Srep + (size_t)b*51200 + tid;
        for(int s = 0; s < 512; s++) acc = fmaf(ws_[s], rp[(size_t)s*100], acc);
        out[b*200 + tid] = acc;
    } else if(tid >= 128 && tid < 228){
        int d = tid - 128;
        float acc = 0.f;
        const float* rp = Crep + (size_t)b*51200 + d;
        for(int s = 0; s < 512; s++) acc = fmaf(wc_[s], rp[(size_t)s*100], acc);
        out[b*200 + 100 + d] = acc;
    }
}

// ---- diagnostic fill (f32) ----
__global__ void k_fill(float* out, int n, float v){
    int i = blockIdx.x*256 + threadIdx.x;
    if(i < n) out[i] = v;
}

extern "C" void kernel_launch(void* const* d_in, const int* in_sizes, int n_in,
                              void* d_out, int out_size, void* d_ws, size_t ws_size,
                              hipStream_t stream)
{
    const float* Srep = (const float*)d_in[0];   // sentence_rep
    const float* Crep = (const float*)d_in[1];   // comment_rep
    const float* Wl   = (const float*)d_in[2];
    const float* Wc   = (const float*)d_in[3];
    const float* Ws   = (const float*)d_in[4];
    const float* whs  = (const float*)d_in[5];
    const float* whc  = (const float*)d_in[6];
    float* out = (float*)d_out;                  // fp32 output

    bool ok = (n_in == 7) &&
              in_sizes[0] == 6553600 && in_sizes[1] == 6553600 &&
              in_sizes[2] == 10000   && in_sizes[3] == 12800 &&
              in_sizes[4] == 12800   && in_sizes[5] == 128 && in_sizes[6] == 128 &&
              out_size == 156672;
    if(!ok){
        k_fill<<<(out_size+255)/256, 256, 0, stream>>>(out, out_size, 1.0f);
        return;
    }

    const size_t L_E_BYTES  = (size_t)128*512*512*2;     // 67.1 MB bf16
    const size_t A1G_ELTS   = (size_t)128*512*100;
    const size_t HBUF_ELTS  = (size_t)128*128*512;
    const size_t SMALL_ELTS = 6*16384 + 7*65536;
    const size_t REQ = L_E_BYTES + (A1G_ELTS + 4*HBUF_ELTS + SMALL_ELTS)*4;  // ~230 MB
    if(ws_size < REQ){
        k_fill<<<(out_size+255)/256, 256, 0, stream>>>(out, out_size, -1.0f);
        return;
    }

    char* base = (char*)d_ws;
    __hip_bfloat16* L_e = (__hip_bfloat16*)base;
    float* fbase = (float*)(base + L_E_BYTES);
    size_t o = 0;
    float* A1g    = fbase + o; o += A1G_ELTS;
    float* Hsa    = fbase + o; o += HBUF_ELTS;   // Hs_a (chain for Hs; log-src for Hc_b)
    float* Hsb0   = fbase + o; o += HBUF_ELTS;   // Hc_a (chain for Hc; log-src for Hs_b)
    float* Ys     = fbase + o; o += HBUF_ELTS;   // gemm_h out -> e_chain in-place -> Hs
    float* Yc     = fbase + o; o += HBUF_ELTS;   // gemm_h out -> e_chain in-place -> Hc
    float* scale_s = fbase + o; o += 16384;
    float* g_s     = fbase + o; o += 16384;
    float* scale_c = fbase + o; o += 16384;
    float* g_c     = fbase + o; o += 16384;
    float* lfA     = fbase + o; o += 16384;
    float* lfB     = fbase + o; o += 16384;
    float* xnsc_s  = fbase + o; o += 65536;
    float* xnsc_c  = fbase + o; o += 65536;
    float* xnraw_c = fbase + o; o += 65536;
    float* alog_s  = fbase + o; o += 65536;
    float* alog_c  = fbase + o; o += 65536;

    // stats
    k_colnorm<<<dim3(128,2), 512, 0, stream>>>(Srep, Crep, scale_s, g_s, scale_c, g_c);
    k_rowstats<<<dim3(65536,2), 128, 0, stream>>>(Srep, Crep, scale_s, scale_c,
                                                  xnsc_s, xnsc_c, xnraw_c);
    // A1g = logmap0(proj(mobius_matvec(Wl, comment_rep))) .* g_s   [B,512,100]
    k_mv_wl<<<65536, 128, 0, stream>>>(Crep, Wl, xnraw_c, g_s, A1g);
    // GEMM1: L_t(bf16) = tanh(A1g @ Srep^T), then row rescale -> L_e
    gemm_t<1,0,1><<<dim3(4,4,128), 256, 0, stream>>>(A1g, (size_t)512*100, 100,
                                                     Srep, (size_t)512*100, 100,
                                                     L_e, (size_t)512*512, 512,
                                                     512, 512, 100, nullptr, 0);
    e_modeL_b16<<<65536, 256, 0, stream>>>(L_e);
    // Hs_a / Hc_a bases via fused GEMM+norm+transpose (both s and c in one launch)
    gemm_mvw<<<dim3(4,256), 256, 0, stream>>>(Srep, Crep, scale_s, scale_c,
                                              xnsc_s, xnsc_c, Ws, Wc, Hsa, Hsb0);
    e3_projrow<<<16384, 256, 0, stream>>>(Hsa, lfA);
    e3_projrow<<<16384, 256, 0, stream>>>(Hsb0, lfB);
    // merged H GEMMs (NN for Hs, NT for Hc)
    gemm_h<<<dim3(1,4,256), 256, 0, stream>>>(Hsa, Hsb0, lfA, lfB, L_e, Ys, Yc);
    // H chains (in-place): Hs = chain(Hsa, Ys); Hc = chain(Hsb0, Yc)
    e_chain<<<16384, 512, 0, stream>>>(Ys, Hsa);
    e_chain<<<16384, 512, 0, stream>>>(Yc, Hsb0);
    // attentions + outputs
    att2<<<128, 256, 0, stream>>>(Ys, whs, alog_s, out + 25600);
    att2<<<128, 256, 0, stream>>>(Yc, whc, alog_c, out + 25600 + 65536);
    co2<<<128, 256, 0, stream>>>(Srep, Crep, alog_s, alog_c, out);
    (void)in_sizes; (void)n_in; (void)ws_size;
}

// Round 13
// 1063.898 us; speedup vs baseline: 3.5255x; 1.1719x over previous
//
#include <hip/hip_runtime.h>
#include <hip/hip_bf16.h>
#include <math.h>

#define MINV 1e-15f
#define MAXN 0.996f   // (1 - 4e-3) / sqrt(c), c = 1

typedef __attribute__((ext_vector_type(8))) short bf16x8;
typedef __attribute__((ext_vector_type(4))) float f32x4;

__device__ __forceinline__ float artanh_f(float x){
    x = fminf(fmaxf(x, -1.0f + 1e-7f), 1.0f - 1e-7f);
    return 0.5f * (log1pf(x) - log1pf(-x));
}

__device__ __forceinline__ unsigned short f2b(float x){
    __hip_bfloat16 h = __float2bfloat16(x);
    return *reinterpret_cast<unsigned short*>(&h);
}

template<int NW>
__device__ __forceinline__ float block_sum(float v, float* sm){
    #pragma unroll
    for(int o=32;o>0;o>>=1) v += __shfl_down(v,o);
    int lane = threadIdx.x & 63, w = threadIdx.x >> 6;
    if(lane==0) sm[w] = v;
    __syncthreads();
    if(w==0){
        float t = (lane<NW)? sm[lane] : 0.0f;
        #pragma unroll
        for(int o=32;o>0;o>>=1) t += __shfl_down(t,o);
        if(lane==0) sm[0] = t;
    }
    __syncthreads();
    float r = sm[0];
    __syncthreads();
    return r;
}

// ---- LDS-tree reductions for 256-thread blocks ----
__device__ __forceinline__ float tree_sum256(float v, float* red){
    int tid = threadIdx.x;
    __syncthreads();
    red[tid] = v;
    __syncthreads();
    for(int o = 128; o > 0; o >>= 1){
        if(tid < o) red[tid] += red[tid + o];
        __syncthreads();
    }
    return red[0];
}
__device__ __forceinline__ float tree_max256(float v, float* red){
    int tid = threadIdx.x;
    __syncthreads();
    red[tid] = v;
    __syncthreads();
    for(int o = 128; o > 0; o >>= 1){
        if(tid < o) red[tid] = fmaxf(red[tid], red[tid + o]);
        __syncthreads();
    }
    return red[0];
}

// ---- per-(b,d) column stats over the 512 positions (s_t / c_t proj+logmap) ----
__global__ void k_colnorm(const float* __restrict__ Srep, const float* __restrict__ Crep,
                          float* scale_s, float* g_s, float* scale_c, float* g_c){
    int b = blockIdx.x;
    bool isC = (blockIdx.y == 1);
    const float* X = isC ? Crep : Srep;
    float* sc = isC ? scale_c : scale_s;
    float* gg = isC ? g_c : g_s;
    int d = threadIdx.x & 127, grp = threadIdx.x >> 7;
    float acc = 0.f;
    if(d < 100){
        const float* base = X + (size_t)b*512*100 + d;
        for(int s = grp; s < 512; s += 4){ float x = base[(size_t)s*100]; acc += x*x; }
    }
    __shared__ float sm[4][128];
    sm[grp][d] = acc;
    __syncthreads();
    if(grp == 0){
        if(d < 100){
            float tot = sm[0][d]+sm[1][d]+sm[2][d]+sm[3][d];
            float n1 = fmaxf(sqrtf(tot), MINV);
            float scale = (n1 > MAXN) ? MAXN/n1 : 1.0f;
            float pn = fminf(n1, MAXN);
            sc[b*128+d] = scale;
            gg[b*128+d] = artanh_f(pn)/pn * scale;
        } else {
            sc[b*128+d] = 0.f;
            gg[b*128+d] = 0.f;
        }
    }
}

// ---- per-row (over D=100) stats: scaled norm (for matvec) + raw norm (for Wl) ----
__global__ void k_rowstats(const float* __restrict__ Srep, const float* __restrict__ Crep,
                           const float* __restrict__ scale_s, const float* __restrict__ scale_c,
                           float* xnsc_s, float* xnsc_c, float* xnraw_c){
    int row = blockIdx.x;               // b*512 + s
    bool isC = (blockIdx.y == 1);
    const float* X = (isC ? Crep : Srep) + (size_t)row*100;
    const float* sc = (isC ? scale_c : scale_s) + (size_t)(row >> 9)*128;
    int d = threadIdx.x;
    float xr = 0.f, xs = 0.f;
    if(d < 100){ float v = X[d]; xr = v*v; float w = sc[d]*v; xs = w*w; }
    __shared__ float sm[2];
    float r2 = block_sum<2>(xr, sm);
    float s2 = block_sum<2>(xs, sm);
    if(threadIdx.x == 0){
        float nr = fmaxf(sqrtf(r2), MINV);
        float ns = fmaxf(sqrtf(s2), MINV);
        if(isC){ xnsc_c[row] = ns; xnraw_c[row] = nr; }
        else   { xnsc_s[row] = ns; }
    }
}

// ---- Wl matvec + mobius finalize + proj + logmap + fold g_s -> A1g [B,512,100] ----
__global__ void k_mv_wl(const float* __restrict__ Crep, const float* __restrict__ Wl,
                        const float* __restrict__ xnraw_c, const float* __restrict__ g_s,
                        float* __restrict__ A1g){
    int row = blockIdx.x;            // b*512 + t
    int b = row >> 9;
    __shared__ float xr[100];
    __shared__ float sm[2];
    int i = threadIdx.x;             // 0..127
    if(i < 100) xr[i] = Crep[(size_t)row*100 + i];
    __syncthreads();
    float mx = 0.f;
    if(i < 100){
        const float* w = Wl + (size_t)i*100;
        for(int d = 0; d < 100; d++) mx = fmaf(w[d], xr[d], mx);
    }
    float ss = block_sum<2>((i < 100) ? mx*mx : 0.f, sm);
    float mxn = fmaxf(sqrtf(ss), MINV);
    float xn = xnraw_c[row];
    float t1 = tanhf(mxn/xn * artanh_f(xn));
    float ps = (t1 > MAXN) ? MAXN/t1 : 1.0f;
    float m = fmaxf(fminf(t1, MAXN), MINV);
    float q = (t1/mxn) * ps * (artanh_f(m)/m);
    if(i < 100) A1g[(size_t)row*100 + i] = q * mx * g_s[b*128 + i];
}

// ---- proj rows (len 512) in place + store logmap factor ----
__global__ void e3_projrow(float* __restrict__ X, float* __restrict__ lf){
    int row = blockIdx.x;
    float* p = X + (size_t)row*512;
    int t = threadIdx.x;
    float v0 = p[t], v1 = p[t+256];
    __shared__ float sm[4];
    float ss = block_sum<4>(v0*v0 + v1*v1, sm);
    float n = fmaxf(sqrtf(ss), MINV);
    if(n > MAXN){ float ps = MAXN/n; p[t] = v0*ps; p[t+256] = v1*ps; }
    float m = fminf(n, MAXN);
    if(t == 0) lf[row] = artanh_f(m)/m;
}

// ---- tiled batched GEMM (validated): C[b] = (msc .* A[b]) x B(^T) ----
template<int BT, int BF16B, int TANHOUT>
__global__ __launch_bounds__(256) void gemm_t(
    const float* __restrict__ A, size_t aStr, int lda,
    const void* __restrict__ Bv, size_t bStr, int ldb,
    void* __restrict__ Cv, size_t cStr, int ldc,
    int M, int N, int Kc,
    const float* __restrict__ msc, int msStr)
{
    int bz = blockIdx.z;
    A += (size_t)bz*aStr;
    const float* Bf = (const float*)Bv + (BF16B ? 0 : (size_t)bz*bStr);
    const __hip_bfloat16* Bh = (const __hip_bfloat16*)Bv + (BF16B ? (size_t)bz*bStr : 0);
    const float* mscb = msc ? msc + (size_t)bz*msStr : nullptr;
    int m0 = blockIdx.x*128, n0 = blockIdx.y*128;
    __shared__ float As[32][132];
    __shared__ float Bs[32][132];
    float acc[8][8];
    #pragma unroll
    for(int i=0;i<8;i++)
        #pragma unroll
        for(int j=0;j<8;j++) acc[i][j] = 0.f;
    int tid = threadIdx.x;
    int ty = tid >> 4, tx = tid & 15;
    for(int k0 = 0; k0 < Kc; k0 += 32){
        for(int idx = tid; idx < 4096; idx += 256){
            int kc = idx & 31;
            int mm = idx >> 5;
            int gk = k0 + kc;
            int gm = m0 + mm;
            float v = 0.f;
            if(gk < Kc){
                v = A[(size_t)gm*lda + gk];
                if(mscb) v *= mscb[gm];
            }
            As[kc][mm] = v;
        }
        for(int idx = tid; idx < 4096; idx += 256){
            int kc, nn;
            if(BT){ kc = idx & 31; nn = idx >> 5; }
            else  { nn = idx & 127; kc = idx >> 7; }
            int gk = k0 + kc;
            int gn = n0 + nn;
            float v = 0.f;
            if(gk < Kc && gn < N){
                size_t off = BT ? ((size_t)gn*ldb + gk) : ((size_t)gk*ldb + gn);
                v = BF16B ? __bfloat162float(Bh[off]) : Bf[off];
            }
            Bs[kc][nn] = v;
        }
        __syncthreads();
        #pragma unroll 4
        for(int kc = 0; kc < 32; kc++){
            float a[8], b[8];
            *(float4*)&a[0] = *(const float4*)&As[kc][ty*8];
            *(float4*)&a[4] = *(const float4*)&As[kc][ty*8+4];
            *(float4*)&b[0] = *(const float4*)&Bs[kc][tx*8];
            *(float4*)&b[4] = *(const float4*)&Bs[kc][tx*8+4];
            #pragma unroll
            for(int i=0;i<8;i++)
                #pragma unroll
                for(int j=0;j<8;j++)
                    acc[i][j] = fmaf(a[i], b[j], acc[i][j]);
        }
        __syncthreads();
    }
    #pragma unroll
    for(int i=0;i<8;i++){
        int m = m0 + ty*8 + i;
        #pragma unroll
        for(int j=0;j<8;j++){
            int n = n0 + tx*8 + j;
            if(n < N){
                if(TANHOUT)
                    ((__hip_bfloat16*)Cv)[(size_t)bz*cStr + (size_t)m*ldc + n] = __float2bfloat16(tanhf(acc[i][j]));
                else
                    ((float*)Cv)[(size_t)bz*cStr + (size_t)m*ldc + n] = acc[i][j];
            }
        }
    }
}

// ---- mobius_matvec(W, scaled rep) fused GEMM + norm + coalesced transpose ----
__global__ __launch_bounds__(256) void gemm_mvw(
    const float* __restrict__ SrepG, const float* __restrict__ CrepG,
    const float* __restrict__ scale_s, const float* __restrict__ scale_c,
    const float* __restrict__ xnsc_s, const float* __restrict__ xnsc_c,
    const float* __restrict__ Ws, const float* __restrict__ Wc,
    float* __restrict__ OutS, float* __restrict__ OutC)
{
    int zz = blockIdx.y;
    int isC = (zz >= 128);
    int b = isC ? zz - 128 : zz;
    const float* A  = (isC ? CrepG : SrepG) + (size_t)b*51200;
    const float* sc = (isC ? scale_c : scale_s) + (size_t)b*128;
    const float* xn = (isC ? xnsc_c : xnsc_s) + (size_t)b*512;
    const float* W  = isC ? Wc : Ws;
    float* Out = (isC ? OutC : OutS) + (size_t)b*65536;
    int m0 = blockIdx.x*128;
    __shared__ float As[32][132];
    __shared__ float Bs[32][132];
    float acc[8][8];
    #pragma unroll
    for(int i=0;i<8;i++)
        #pragma unroll
        for(int j=0;j<8;j++) acc[i][j] = 0.f;
    int tid = threadIdx.x;
    int ty = tid >> 4, tx = tid & 15;
    for(int k0 = 0; k0 < 100; k0 += 32){
        for(int idx = tid; idx < 4096; idx += 256){
            int kc = idx & 31;
            int mm = idx >> 5;
            int gk = k0 + kc;
            float v = 0.f;
            if(gk < 100) v = A[(size_t)(m0+mm)*100 + gk] * sc[gk];
            As[kc][mm] = v;
        }
        for(int idx = tid; idx < 4096; idx += 256){
            int kc = idx & 31;
            int nn = idx >> 5;
            int gk = k0 + kc;
            float v = 0.f;
            if(gk < 100) v = W[(size_t)nn*100 + gk];
            Bs[kc][nn] = v;
        }
        __syncthreads();
        #pragma unroll 4
        for(int kc = 0; kc < 32; kc++){
            float a[8], bb[8];
            *(float4*)&a[0] = *(const float4*)&As[kc][ty*8];
            *(float4*)&a[4] = *(const float4*)&As[kc][ty*8+4];
            *(float4*)&bb[0] = *(const float4*)&Bs[kc][tx*8];
            *(float4*)&bb[4] = *(const float4*)&Bs[kc][tx*8+4];
            #pragma unroll
            for(int i=0;i<8;i++)
                #pragma unroll
                for(int j=0;j<8;j++)
                    acc[i][j] = fmaf(a[i], bb[j], acc[i][j]);
        }
        __syncthreads();
    }
    float mult[8];
    #pragma unroll
    for(int i=0;i<8;i++){
        float ps = 0.f;
        #pragma unroll
        for(int j=0;j<8;j++) ps = fmaf(acc[i][j], acc[i][j], ps);
        ps += __shfl_xor(ps, 1);
        ps += __shfl_xor(ps, 2);
        ps += __shfl_xor(ps, 4);
        ps += __shfl_xor(ps, 8);
        float mxn = fmaxf(sqrtf(ps), MINV);
        float x = xn[m0 + ty*8 + i];
        float t1 = tanhf(mxn/x * artanh_f(x));
        mult[i] = t1/mxn;
    }
    for(int c = 0; c < 4; c++){
        __syncthreads();
        if((tx >> 2) == c){
            #pragma unroll
            for(int j=0;j<8;j++)
                #pragma unroll
                for(int i=0;i<8;i++)
                    Bs[(tx&3)*8 + j][ty*8 + i] = acc[i][j]*mult[i];
        }
        __syncthreads();
        for(int w = tid; w < 4096; w += 256){
            int kr = w >> 7, sl = w & 127;
            Out[(size_t)(c*32 + kr)*512 + m0 + sl] = Bs[kr][sl];
        }
    }
}

// ---- MFMA H GEMMs: z=0 -> Ys = (lfB.*Hsb0[b]) @ L_e[b]      (NN)
//                    z=1 -> Yc = (lfA.*Hsa[b]) @ L_e[b]^T     (NT)
// Tile M=128 x N=128, K_STEP=64; 4 waves of 64x64; mfma_f32_16x16x32_bf16.
__global__ __launch_bounds__(256) void gemm_h_mfma(
    const float* __restrict__ Hsa, const float* __restrict__ Hsb0,
    const float* __restrict__ lfA, const float* __restrict__ lfB,
    const __hip_bfloat16* __restrict__ L_e,
    float* __restrict__ Ys, float* __restrict__ Yc)
{
    int BT = blockIdx.z;
    int b = blockIdx.y;
    int n0 = blockIdx.x * 128;
    const float* A = (BT ? Hsa : Hsb0) + (size_t)b*65536;
    const float* msc = (BT ? lfA : lfB) + (size_t)b*128;
    const unsigned short* Lb = (const unsigned short*)L_e + (size_t)b*262144;
    float* C = (BT ? Yc : Ys) + (size_t)b*65536;

    __shared__ unsigned short As[128][72];   // [m][k], k-contiguous
    __shared__ unsigned short Bs[128][72];   // [n][k], k-contiguous

    int tid = threadIdx.x;
    int lane = tid & 63, w = tid >> 6;
    int wm = (w >> 1) * 64, wn = (w & 1) * 64;
    int lr = lane & 15, lg = lane >> 4;

    f32x4 acc[4][4];
    #pragma unroll
    for(int i=0;i<4;i++)
        #pragma unroll
        for(int j=0;j<4;j++) acc[i][j] = (f32x4){0.f,0.f,0.f,0.f};

    for(int k0 = 0; k0 < 512; k0 += 64){
        // stage A: 128m x 64k fp32 -> bf16 (msc folded)
        #pragma unroll
        for(int r = 0; r < 8; r++){
            int gi = tid + r*256;            // 0..2047
            int m = gi >> 4, kq = (gi & 15) * 4;
            float4 v = *(const float4*)&A[(size_t)m*512 + k0 + kq];
            float s = msc[m];
            unsigned long long pk =
                  (unsigned long long)f2b(v.x*s)
                | ((unsigned long long)f2b(v.y*s) << 16)
                | ((unsigned long long)f2b(v.z*s) << 32)
                | ((unsigned long long)f2b(v.w*s) << 48);
            *(unsigned long long*)&As[m][kq] = pk;
        }
        // stage B
        if(BT){
            // Bs[n][k] = L_e[n0+n][k0+k] : rows contiguous -> b128 copies
            #pragma unroll
            for(int r = 0; r < 4; r++){
                int gi = tid + r*256;        // 0..1023
                int n = gi >> 3, ck = (gi & 7) * 8;
                *(int4*)&Bs[n][ck] = *(const int4*)&Lb[(size_t)(n0+n)*512 + k0 + ck];
            }
        } else {
            // Bs[n][k] = L_e[k0+k][n0+n] : lane-per-k, 8 n's per iter
            #pragma unroll
            for(int r = 0; r < 4; r++){
                int nb = (w*4 + r)*8;
                unsigned short tmp[8];
                *(int4*)tmp = *(const int4*)&Lb[(size_t)(k0+lane)*512 + n0 + nb];
                #pragma unroll
                for(int j=0;j<8;j++) Bs[nb+j][lane] = tmp[j];
            }
        }
        __syncthreads();
        #pragma unroll
        for(int kh = 0; kh < 2; kh++){
            bf16x8 av[4], bv[4];
            #pragma unroll
            for(int f=0;f<4;f++){
                av[f] = *(const bf16x8*)&As[wm + f*16 + lr][kh*32 + lg*8];
                bv[f] = *(const bf16x8*)&Bs[wn + f*16 + lr][kh*32 + lg*8];
            }
            #pragma unroll
            for(int mf=0;mf<4;mf++)
                #pragma unroll
                for(int nf=0;nf<4;nf++)
                    acc[mf][nf] = __builtin_amdgcn_mfma_f32_16x16x32_bf16(
                                      av[mf], bv[nf], acc[mf][nf], 0, 0, 0);
        }
        __syncthreads();
    }
    #pragma unroll
    for(int mf=0;mf<4;mf++){
        #pragma unroll
        for(int nf=0;nf<4;nf++){
            #pragma unroll
            for(int r=0;r<4;r++){
                int m = wm + mf*16 + lg*4 + r;
                int n = n0 + wn + nf*16 + lr;
                C[(size_t)m*512 + n] = acc[mf][nf][r];
            }
        }
    }
}

// ---- L epilogue on bf16 tanh(L) rows ----
__global__ void e_modeL_b16(__hip_bfloat16* __restrict__ X){
    int row = blockIdx.x;
    __hip_bfloat16* p = X + (size_t)row*512;
    int t = threadIdx.x;
    float v0 = __bfloat162float(p[t]);
    float v1 = __bfloat162float(p[t+256]);
    __shared__ float sm[4];
    float ss = block_sum<4>(v0*v0 + v1*v1, sm);
    float un = fmaxf(sqrtf(ss), MINV);
    float pn = fminf(tanhf(un), MAXN);
    float f = artanh_f(pn)/un;
    p[t] = __float2bfloat16(f*v0);
    p[t+256] = __float2bfloat16(f*v1);
}

// ---- H epilogue chain ----
__global__ void e_chain(float* __restrict__ Y, const float* __restrict__ X){
    int row = blockIdx.x;               // b*128 + k
    __shared__ float sm[8];
    int t = threadIdx.x;                // 0..511
    size_t rowoff = (size_t)row*512;
    float acc = Y[rowoff + t];
    float ss = block_sum<8>(acc*acc, sm);
    float un = fmaxf(sqrtf(ss), MINV);
    float y = fminf(tanhf(un), MAXN)/un * acc;
    float x = X[rowoff + t];
    float x2 = block_sum<8>(x*x, sm);
    float y2 = block_sum<8>(y*y, sm);
    float xy = block_sum<8>(x*y, sm);
    float a  = 1.f + 2.f*xy + y2;
    float bb = 1.f - x2;
    float den = fmaxf(1.f + 2.f*xy + x2*y2, MINV);
    float z = (a*x + bb*y)/den;
    float zz = block_sum<8>(z*z, sm);
    float n = fmaxf(sqrtf(zz), MINV);
    float ps = (n > MAXN) ? MAXN/n : 1.f;
    float mm = fminf(n, MAXN);
    float lf2 = artanh_f(mm)/mm * ps;
    float v = tanhf(lf2*z);
    float vv = block_sum<8>(v*v, sm);
    float un2 = fmaxf(sqrtf(vv), MINV);
    float f2 = fminf(tanhf(un2), MAXN)/un2;
    Y[rowoff + t] = f2*v;
}

// ---- attention (f32 out) ----
__global__ void att2(const float* __restrict__ H, const float* __restrict__ wh,
                     float* __restrict__ alog, float* __restrict__ outAtt){
    int b = blockIdx.x;
    int tid = threadIdx.x;
    __shared__ float whl[128];
    __shared__ float red[256];
    if(tid < 128) whl[tid] = wh[tid];
    __syncthreads();
    float res2[2];
    #pragma unroll
    for(int h = 0; h < 2; h++){
        int s = tid + h*256;
        const float* hp = H + (size_t)b*65536 + s;
        float mx = 0.f, x2 = 0.f;
        for(int k = 0; k < 128; k++){
            float v = hp[(size_t)k*512];
            mx = fmaf(whl[k], v, mx);
            x2 = fmaf(v, v, x2);
        }
        float xn  = fmaxf(sqrtf(x2), MINV);
        float mxn = fmaxf(fabsf(mx), MINV);
        float t1 = tanhf(mxn/xn * artanh_f(xn));
        res2[h] = t1 * (mx/mxn);
    }
    float rr = tree_sum256(res2[0]*res2[0] + res2[1]*res2[1], red);
    float n = fmaxf(sqrtf(rr), MINV);
    float ps = (n > MAXN) ? MAXN/n : 1.f;
    float m = fminf(n, MAXN);
    float lfw = artanh_f(m)/m * ps;
    float w0 = lfw*res2[0], w1 = lfw*res2[1];
    float wmax = tree_max256(fmaxf(w0, w1), red);
    float e0 = expf(w0 - wmax), e1 = expf(w1 - wmax);
    float es = tree_sum256(e0 + e1, red);
    float p0 = e0/es, p1 = e1/es;
    float pp = tree_sum256(p0*p0 + p1*p1, red);
    float un = fmaxf(sqrtf(pp), MINV);
    float th = tanhf(un);
    float f = fminf(th, MAXN)/un;
    float A0 = f*p0, A1 = f*p1;
    outAtt[b*512 + tid]       = A0;
    outAtt[b*512 + tid + 256] = A1;
    float m2 = fmaxf(fminf(th, MAXN), MINV);
    float fl = artanh_f(m2)/m2;
    alog[b*512 + tid]       = fl*A0;
    alog[b*512 + tid + 256] = fl*A1;
}

// ---- co kernel ----
__global__ void co2(const float* __restrict__ Srep, const float* __restrict__ Crep,
                    const float* __restrict__ alog_s, const float* __restrict__ alog_c,
                    float* __restrict__ out){
    int b = blockIdx.x, tid = threadIdx.x;
    __shared__ float ws_[512], wc_[512];
    #pragma unroll
    for(int h = 0; h < 2; h++){
        int s = tid + h*256;
        const float* sp = Srep + (size_t)(b*512 + s)*100;
        const float* cp = Crep + (size_t)(b*512 + s)*100;
        float s2 = 0.f, c2 = 0.f;
        for(int d = 0; d < 100; d++){
            float a = sp[d]; s2 = fmaf(a, a, s2);
            float e = cp[d]; c2 = fmaf(e, e, c2);
        }
        float nsr = fmaxf(sqrtf(s2), MINV);
        float ncr = fmaxf(sqrtf(c2), MINV);
        ws_[s] = alog_s[b*512 + s] * (artanh_f(nsr)/nsr);
        wc_[s] = alog_c[b*512 + s] * (artanh_f(ncr)/ncr);
    }
    __syncthreads();
    if(tid < 100){
        float acc = 0.f;
        const float* rp = Srep + (size_t)b*51200 + tid;
        for(int s = 0; s < 512; s++) acc = fmaf(ws_[s], rp[(size_t)s*100], acc);
        out[b*200 + tid] = acc;
    } else if(tid >= 128 && tid < 228){
        int d = tid - 128;
        float acc = 0.f;
        const float* rp = Crep + (size_t)b*51200 + d;
        for(int s = 0; s < 512; s++) acc = fmaf(wc_[s], rp[(size_t)s*100], acc);
        out[b*200 + 100 + d] = acc;
    }
}

// ---- diagnostic fill (f32) ----
__global__ void k_fill(float* out, int n, float v){
    int i = blockIdx.x*256 + threadIdx.x;
    if(i < n) out[i] = v;
}

extern "C" void kernel_launch(void* const* d_in, const int* in_sizes, int n_in,
                              void* d_out, int out_size, void* d_ws, size_t ws_size,
                              hipStream_t stream)
{
    const float* Srep = (const float*)d_in[0];   // sentence_rep
    const float* Crep = (const float*)d_in[1];   // comment_rep
    const float* Wl   = (const float*)d_in[2];
    const float* Wc   = (const float*)d_in[3];
    const float* Ws   = (const float*)d_in[4];
    const float* whs  = (const float*)d_in[5];
    const float* whc  = (const float*)d_in[6];
    float* out = (float*)d_out;                  // fp32 output

    bool ok = (n_in == 7) &&
              in_sizes[0] == 6553600 && in_sizes[1] == 6553600 &&
              in_sizes[2] == 10000   && in_sizes[3] == 12800 &&
              in_sizes[4] == 12800   && in_sizes[5] == 128 && in_sizes[6] == 128 &&
              out_size == 156672;
    if(!ok){
        k_fill<<<(out_size+255)/256, 256, 0, stream>>>(out, out_size, 1.0f);
        return;
    }

    const size_t L_E_BYTES  = (size_t)128*512*512*2;     // 67.1 MB bf16
    const size_t A1G_ELTS   = (size_t)128*512*100;
    const size_t HBUF_ELTS  = (size_t)128*128*512;
    const size_t SMALL_ELTS = 6*16384 + 7*65536;
    const size_t REQ = L_E_BYTES + (A1G_ELTS + 4*HBUF_ELTS + SMALL_ELTS)*4;  // ~230 MB
    if(ws_size < REQ){
        k_fill<<<(out_size+255)/256, 256, 0, stream>>>(out, out_size, -1.0f);
        return;
    }

    char* base = (char*)d_ws;
    __hip_bfloat16* L_e = (__hip_bfloat16*)base;
    float* fbase = (float*)(base + L_E_BYTES);
    size_t o = 0;
    float* A1g    = fbase + o; o += A1G_ELTS;
    float* Hsa    = fbase + o; o += HBUF_ELTS;   // Hs_a (chain for Hs; log-src for Hc_b)
    float* Hsb0   = fbase + o; o += HBUF_ELTS;   // Hc_a (chain for Hc; log-src for Hs_b)
    float* Ys     = fbase + o; o += HBUF_ELTS;
    float* Yc     = fbase + o; o += HBUF_ELTS;
    float* scale_s = fbase + o; o += 16384;
    float* g_s     = fbase + o; o += 16384;
    float* scale_c = fbase + o; o += 16384;
    float* g_c     = fbase + o; o += 16384;
    float* lfA     = fbase + o; o += 16384;
    float* lfB     = fbase + o; o += 16384;
    float* xnsc_s  = fbase + o; o += 65536;
    float* xnsc_c  = fbase + o; o += 65536;
    float* xnraw_c = fbase + o; o += 65536;
    float* alog_s  = fbase + o; o += 65536;
    float* alog_c  = fbase + o; o += 65536;

    // stats
    k_colnorm<<<dim3(128,2), 512, 0, stream>>>(Srep, Crep, scale_s, g_s, scale_c, g_c);
    k_rowstats<<<dim3(65536,2), 128, 0, stream>>>(Srep, Crep, scale_s, scale_c,
                                                  xnsc_s, xnsc_c, xnraw_c);
    // A1g = logmap0(proj(mobius_matvec(Wl, comment_rep))) .* g_s   [B,512,100]
    k_mv_wl<<<65536, 128, 0, stream>>>(Crep, Wl, xnraw_c, g_s, A1g);
    // GEMM1: L_t(bf16) = tanh(A1g @ Srep^T), then row rescale -> L_e
    gemm_t<1,0,1><<<dim3(4,4,128), 256, 0, stream>>>(A1g, (size_t)512*100, 100,
                                                     Srep, (size_t)512*100, 100,
                                                     L_e, (size_t)512*512, 512,
                                                     512, 512, 100, nullptr, 0);
    e_modeL_b16<<<65536, 256, 0, stream>>>(L_e);
    // Hs_a / Hc_a bases via fused GEMM+norm+transpose
    gemm_mvw<<<dim3(4,256), 256, 0, stream>>>(Srep, Crep, scale_s, scale_c,
                                              xnsc_s, xnsc_c, Ws, Wc, Hsa, Hsb0);
    e3_projrow<<<16384, 256, 0, stream>>>(Hsa, lfA);
    e3_projrow<<<16384, 256, 0, stream>>>(Hsb0, lfB);
    // merged H GEMMs via MFMA (z=0: NN -> Ys, z=1: NT -> Yc)
    gemm_h_mfma<<<dim3(4,128,2), 256, 0, stream>>>(Hsa, Hsb0, lfA, lfB, L_e, Ys, Yc);
    // H chains (in-place)
    e_chain<<<16384, 512, 0, stream>>>(Ys, Hsa);
    e_chain<<<16384, 512, 0, stream>>>(Yc, Hsb0);
    // attentions + outputs
    att2<<<128, 256, 0, stream>>>(Ys, whs, alog_s, out + 25600);
    att2<<<128, 256, 0, stream>>>(Yc, whc, alog_c, out + 25600 + 65536);
    co2<<<128, 256, 0, stream>>>(Srep, Crep, alog_s, alog_c, out);
    (void)in_sizes; (void)n_in; (void)ws_size;
}

// Round 14
// 864.571 us; speedup vs baseline: 4.3383x; 1.2306x over previous
//
#include <hip/hip_runtime.h>
#include <hip/hip_bf16.h>
#include <math.h>

#define MINV 1e-15f
#define MAXN 0.996f   // (1 - 4e-3) / sqrt(c), c = 1

typedef __attribute__((ext_vector_type(8))) short bf16x8;
typedef __attribute__((ext_vector_type(4))) float f32x4;

__device__ __forceinline__ float artanh_f(float x){
    x = fminf(fmaxf(x, -1.0f + 1e-7f), 1.0f - 1e-7f);
    return 0.5f * (log1pf(x) - log1pf(-x));
}

__device__ __forceinline__ unsigned short f2b(float x){
    __hip_bfloat16 h = __float2bfloat16(x);
    return *reinterpret_cast<unsigned short*>(&h);
}

template<int NW>
__device__ __forceinline__ float block_sum(float v, float* sm){
    #pragma unroll
    for(int o=32;o>0;o>>=1) v += __shfl_down(v,o);
    int lane = threadIdx.x & 63, w = threadIdx.x >> 6;
    if(lane==0) sm[w] = v;
    __syncthreads();
    if(w==0){
        float t = (lane<NW)? sm[lane] : 0.0f;
        #pragma unroll
        for(int o=32;o>0;o>>=1) t += __shfl_down(t,o);
        if(lane==0) sm[0] = t;
    }
    __syncthreads();
    float r = sm[0];
    __syncthreads();
    return r;
}

// ---- LDS-tree reductions for 256-thread blocks ----
__device__ __forceinline__ float tree_sum256(float v, float* red){
    int tid = threadIdx.x;
    __syncthreads();
    red[tid] = v;
    __syncthreads();
    for(int o = 128; o > 0; o >>= 1){
        if(tid < o) red[tid] += red[tid + o];
        __syncthreads();
    }
    return red[0];
}
__device__ __forceinline__ float tree_max256(float v, float* red){
    int tid = threadIdx.x;
    __syncthreads();
    red[tid] = v;
    __syncthreads();
    for(int o = 128; o > 0; o >>= 1){
        if(tid < o) red[tid] = fmaxf(red[tid], red[tid + o]);
        __syncthreads();
    }
    return red[0];
}

// ---- per-(b,d) column stats over the 512 positions (s_t / c_t proj+logmap) ----
__global__ void k_colnorm(const float* __restrict__ Srep, const float* __restrict__ Crep,
                          float* scale_s, float* g_s, float* scale_c, float* g_c){
    int b = blockIdx.x;
    bool isC = (blockIdx.y == 1);
    const float* X = isC ? Crep : Srep;
    float* sc = isC ? scale_c : scale_s;
    float* gg = isC ? g_c : g_s;
    int d = threadIdx.x & 127, grp = threadIdx.x >> 7;
    float acc = 0.f;
    if(d < 100){
        const float* base = X + (size_t)b*512*100 + d;
        for(int s = grp; s < 512; s += 4){ float x = base[(size_t)s*100]; acc += x*x; }
    }
    __shared__ float sm[4][128];
    sm[grp][d] = acc;
    __syncthreads();
    if(grp == 0){
        if(d < 100){
            float tot = sm[0][d]+sm[1][d]+sm[2][d]+sm[3][d];
            float n1 = fmaxf(sqrtf(tot), MINV);
            float scale = (n1 > MAXN) ? MAXN/n1 : 1.0f;
            float pn = fminf(n1, MAXN);
            sc[b*128+d] = scale;
            gg[b*128+d] = artanh_f(pn)/pn * scale;
        } else {
            sc[b*128+d] = 0.f;
            gg[b*128+d] = 0.f;
        }
    }
}

// ---- per-row (over D=100) stats: scaled norm (for matvec) + raw norm (for Wl) ----
__global__ void k_rowstats(const float* __restrict__ Srep, const float* __restrict__ Crep,
                           const float* __restrict__ scale_s, const float* __restrict__ scale_c,
                           float* xnsc_s, float* xnsc_c, float* xnraw_c){
    int row = blockIdx.x;               // b*512 + s
    bool isC = (blockIdx.y == 1);
    const float* X = (isC ? Crep : Srep) + (size_t)row*100;
    const float* sc = (isC ? scale_c : scale_s) + (size_t)(row >> 9)*128;
    int d = threadIdx.x;
    float xr = 0.f, xs = 0.f;
    if(d < 100){ float v = X[d]; xr = v*v; float w = sc[d]*v; xs = w*w; }
    __shared__ float sm[2];
    float r2 = block_sum<2>(xr, sm);
    float s2 = block_sum<2>(xs, sm);
    if(threadIdx.x == 0){
        float nr = fmaxf(sqrtf(r2), MINV);
        float ns = fmaxf(sqrtf(s2), MINV);
        if(isC){ xnsc_c[row] = ns; xnraw_c[row] = nr; }
        else   { xnsc_s[row] = ns; }
    }
}

// ---- Wl mobius_matvec as tiled GEMM + fused q/g_s epilogue -> A1g [B,512,100] ----
// A = Crep[b] [512,100]; B = Wl [100,100] (BT layout); per-m norm over the 100 outputs.
__global__ __launch_bounds__(256) void gemm_wl(
    const float* __restrict__ Crep, const float* __restrict__ Wl,
    const float* __restrict__ xnraw_c, const float* __restrict__ g_s,
    float* __restrict__ A1g)
{
    int b = blockIdx.y;
    int m0 = blockIdx.x*128;
    const float* A = Crep + (size_t)b*51200;
    __shared__ float As[32][132];
    __shared__ float Bs[32][132];
    float acc[8][8];
    #pragma unroll
    for(int i=0;i<8;i++)
        #pragma unroll
        for(int j=0;j<8;j++) acc[i][j] = 0.f;
    int tid = threadIdx.x;
    int ty = tid >> 4, tx = tid & 15;
    for(int k0 = 0; k0 < 100; k0 += 32){
        for(int idx = tid; idx < 4096; idx += 256){
            int kc = idx & 31;
            int mm = idx >> 5;
            int gk = k0 + kc;
            As[kc][mm] = (gk < 100) ? A[(size_t)(m0+mm)*100 + gk] : 0.f;
        }
        for(int idx = tid; idx < 4096; idx += 256){
            int kc = idx & 31;
            int nn = idx >> 5;
            int gk = k0 + kc;
            Bs[kc][nn] = (gk < 100 && nn < 100) ? Wl[(size_t)nn*100 + gk] : 0.f;
        }
        __syncthreads();
        #pragma unroll 4
        for(int kc = 0; kc < 32; kc++){
            float a[8], bb[8];
            *(float4*)&a[0] = *(const float4*)&As[kc][ty*8];
            *(float4*)&a[4] = *(const float4*)&As[kc][ty*8+4];
            *(float4*)&bb[0] = *(const float4*)&Bs[kc][tx*8];
            *(float4*)&bb[4] = *(const float4*)&Bs[kc][tx*8+4];
            #pragma unroll
            for(int i=0;i<8;i++)
                #pragma unroll
                for(int j=0;j<8;j++)
                    acc[i][j] = fmaf(a[i], bb[j], acc[i][j]);
        }
        __syncthreads();
    }
    const float* xnb = xnraw_c + (size_t)b*512;
    const float* gsb = g_s + (size_t)b*128;
    #pragma unroll
    for(int i=0;i<8;i++){
        float ss = 0.f;
        #pragma unroll
        for(int j=0;j<8;j++) ss = fmaf(acc[i][j], acc[i][j], ss);
        ss += __shfl_xor(ss, 1);
        ss += __shfl_xor(ss, 2);
        ss += __shfl_xor(ss, 4);
        ss += __shfl_xor(ss, 8);
        int m = m0 + ty*8 + i;
        float mxn = fmaxf(sqrtf(ss), MINV);
        float xn = xnb[m];
        float t1 = tanhf(mxn/xn * artanh_f(xn));
        float ps = (t1 > MAXN) ? MAXN/t1 : 1.0f;
        float mm = fmaxf(fminf(t1, MAXN), MINV);
        float q = (t1/mxn) * ps * (artanh_f(mm)/mm);
        float* orow = A1g + ((size_t)b*512 + m)*100;
        #pragma unroll
        for(int j=0;j<8;j++){
            int n = tx*8 + j;
            if(n < 100) orow[n] = q*acc[i][j]*gsb[n];
        }
    }
}

// ---- GEMM1 via MFMA: L_e(bf16) = tanh( A1g[b] @ Srep[b]^T ), K=100 padded to 128.
// Same validated core as gemm_h_mfma (4 waves x 64x64, 16x16x32 bf16). ----
__global__ __launch_bounds__(256) void gemm_L_mfma(
    const float* __restrict__ A1g, const float* __restrict__ Srep,
    __hip_bfloat16* __restrict__ L_e)
{
    int b = blockIdx.z;
    int m0 = blockIdx.y * 128, n0 = blockIdx.x * 128;
    const float* Ab = A1g + (size_t)b*51200;
    const float* Bb = Srep + (size_t)b*51200;
    unsigned short* Cb = (unsigned short*)L_e + (size_t)b*262144;

    __shared__ unsigned short As[128][72];
    __shared__ unsigned short Bs[128][72];

    int tid = threadIdx.x;
    int lane = tid & 63, w = tid >> 6;
    int wm = (w >> 1) * 64, wn = (w & 1) * 64;
    int lr = lane & 15, lg = lane >> 4;

    f32x4 acc[4][4];
    #pragma unroll
    for(int i=0;i<4;i++)
        #pragma unroll
        for(int j=0;j<4;j++) acc[i][j] = (f32x4){0.f,0.f,0.f,0.f};

    for(int k0 = 0; k0 < 128; k0 += 64){
        #pragma unroll
        for(int r = 0; r < 8; r++){
            int gi = tid + r*256;            // 0..2047
            int m = gi >> 4, kq = (gi & 15) * 4;
            int gk = k0 + kq;
            float4 v = {0.f,0.f,0.f,0.f};
            if(gk < 100) v = *(const float4*)&Ab[(size_t)(m0+m)*100 + gk];
            unsigned long long pk =
                  (unsigned long long)f2b(v.x)
                | ((unsigned long long)f2b(v.y) << 16)
                | ((unsigned long long)f2b(v.z) << 32)
                | ((unsigned long long)f2b(v.w) << 48);
            *(unsigned long long*)&As[m][kq] = pk;
        }
        #pragma unroll
        for(int r = 0; r < 8; r++){
            int gi = tid + r*256;
            int n = gi >> 4, kq = (gi & 15) * 4;
            int gk = k0 + kq;
            float4 v = {0.f,0.f,0.f,0.f};
            if(gk < 100) v = *(const float4*)&Bb[(size_t)(n0+n)*100 + gk];
            unsigned long long pk =
                  (unsigned long long)f2b(v.x)
                | ((unsigned long long)f2b(v.y) << 16)
                | ((unsigned long long)f2b(v.z) << 32)
                | ((unsigned long long)f2b(v.w) << 48);
            *(unsigned long long*)&Bs[n][kq] = pk;
        }
        __syncthreads();
        #pragma unroll
        for(int kh = 0; kh < 2; kh++){
            bf16x8 av[4], bv[4];
            #pragma unroll
            for(int f=0;f<4;f++){
                av[f] = *(const bf16x8*)&As[wm + f*16 + lr][kh*32 + lg*8];
                bv[f] = *(const bf16x8*)&Bs[wn + f*16 + lr][kh*32 + lg*8];
            }
            #pragma unroll
            for(int mf=0;mf<4;mf++)
                #pragma unroll
                for(int nf=0;nf<4;nf++)
                    acc[mf][nf] = __builtin_amdgcn_mfma_f32_16x16x32_bf16(
                                      av[mf], bv[nf], acc[mf][nf], 0, 0, 0);
        }
        __syncthreads();
    }
    #pragma unroll
    for(int mf=0;mf<4;mf++){
        #pragma unroll
        for(int nf=0;nf<4;nf++){
            #pragma unroll
            for(int r=0;r<4;r++){
                int m = m0 + wm + mf*16 + lg*4 + r;
                int n = n0 + wn + nf*16 + lr;
                Cb[(size_t)m*512 + n] = f2b(tanhf(acc[mf][nf][r]));
            }
        }
    }
}

// ---- mobius_matvec(W, scaled rep) fused GEMM + norm + coalesced transpose ----
__global__ __launch_bounds__(256) void gemm_mvw(
    const float* __restrict__ SrepG, const float* __restrict__ CrepG,
    const float* __restrict__ scale_s, const float* __restrict__ scale_c,
    const float* __restrict__ xnsc_s, const float* __restrict__ xnsc_c,
    const float* __restrict__ Ws, const float* __restrict__ Wc,
    float* __restrict__ OutS, float* __restrict__ OutC)
{
    int zz = blockIdx.y;
    int isC = (zz >= 128);
    int b = isC ? zz - 128 : zz;
    const float* A  = (isC ? CrepG : SrepG) + (size_t)b*51200;
    const float* sc = (isC ? scale_c : scale_s) + (size_t)b*128;
    const float* xn = (isC ? xnsc_c : xnsc_s) + (size_t)b*512;
    const float* W  = isC ? Wc : Ws;
    float* Out = (isC ? OutC : OutS) + (size_t)b*65536;
    int m0 = blockIdx.x*128;
    __shared__ float As[32][132];
    __shared__ float Bs[32][132];
    float acc[8][8];
    #pragma unroll
    for(int i=0;i<8;i++)
        #pragma unroll
        for(int j=0;j<8;j++) acc[i][j] = 0.f;
    int tid = threadIdx.x;
    int ty = tid >> 4, tx = tid & 15;
    for(int k0 = 0; k0 < 100; k0 += 32){
        for(int idx = tid; idx < 4096; idx += 256){
            int kc = idx & 31;
            int mm = idx >> 5;
            int gk = k0 + kc;
            float v = 0.f;
            if(gk < 100) v = A[(size_t)(m0+mm)*100 + gk] * sc[gk];
            As[kc][mm] = v;
        }
        for(int idx = tid; idx < 4096; idx += 256){
            int kc = idx & 31;
            int nn = idx >> 5;
            int gk = k0 + kc;
            float v = 0.f;
            if(gk < 100) v = W[(size_t)nn*100 + gk];
            Bs[kc][nn] = v;
        }
        __syncthreads();
        #pragma unroll 4
        for(int kc = 0; kc < 32; kc++){
            float a[8], bb[8];
            *(float4*)&a[0] = *(const float4*)&As[kc][ty*8];
            *(float4*)&a[4] = *(const float4*)&As[kc][ty*8+4];
            *(float4*)&bb[0] = *(const float4*)&Bs[kc][tx*8];
            *(float4*)&bb[4] = *(const float4*)&Bs[kc][tx*8+4];
            #pragma unroll
            for(int i=0;i<8;i++)
                #pragma unroll
                for(int j=0;j<8;j++)
                    acc[i][j] = fmaf(a[i], bb[j], acc[i][j]);
        }
        __syncthreads();
    }
    float mult[8];
    #pragma unroll
    for(int i=0;i<8;i++){
        float ps = 0.f;
        #pragma unroll
        for(int j=0;j<8;j++) ps = fmaf(acc[i][j], acc[i][j], ps);
        ps += __shfl_xor(ps, 1);
        ps += __shfl_xor(ps, 2);
        ps += __shfl_xor(ps, 4);
        ps += __shfl_xor(ps, 8);
        float mxn = fmaxf(sqrtf(ps), MINV);
        float x = xn[m0 + ty*8 + i];
        float t1 = tanhf(mxn/x * artanh_f(x));
        mult[i] = t1/mxn;
    }
    for(int c = 0; c < 4; c++){
        __syncthreads();
        if((tx >> 2) == c){
            #pragma unroll
            for(int j=0;j<8;j++)
                #pragma unroll
                for(int i=0;i<8;i++)
                    Bs[(tx&3)*8 + j][ty*8 + i] = acc[i][j]*mult[i];
        }
        __syncthreads();
        for(int w = tid; w < 4096; w += 256){
            int kr = w >> 7, sl = w & 127;
            Out[(size_t)(c*32 + kr)*512 + m0 + sl] = Bs[kr][sl];
        }
    }
}

// ---- MFMA H GEMMs: z=0 -> Ys = (lfB.*Hsb0[b]) @ L_e[b]      (NN)
//                    z=1 -> Yc = (lfA.*Hsa[b]) @ L_e[b]^T     (NT) ----
__global__ __launch_bounds__(256) void gemm_h_mfma(
    const float* __restrict__ Hsa, const float* __restrict__ Hsb0,
    const float* __restrict__ lfA, const float* __restrict__ lfB,
    const __hip_bfloat16* __restrict__ L_e,
    float* __restrict__ Ys, float* __restrict__ Yc)
{
    int BT = blockIdx.z;
    int b = blockIdx.y;
    int n0 = blockIdx.x * 128;
    const float* A = (BT ? Hsa : Hsb0) + (size_t)b*65536;
    const float* msc = (BT ? lfA : lfB) + (size_t)b*128;
    const unsigned short* Lb = (const unsigned short*)L_e + (size_t)b*262144;
    float* C = (BT ? Yc : Ys) + (size_t)b*65536;

    __shared__ unsigned short As[128][72];
    __shared__ unsigned short Bs[128][72];

    int tid = threadIdx.x;
    int lane = tid & 63, w = tid >> 6;
    int wm = (w >> 1) * 64, wn = (w & 1) * 64;
    int lr = lane & 15, lg = lane >> 4;

    f32x4 acc[4][4];
    #pragma unroll
    for(int i=0;i<4;i++)
        #pragma unroll
        for(int j=0;j<4;j++) acc[i][j] = (f32x4){0.f,0.f,0.f,0.f};

    for(int k0 = 0; k0 < 512; k0 += 64){
        #pragma unroll
        for(int r = 0; r < 8; r++){
            int gi = tid + r*256;
            int m = gi >> 4, kq = (gi & 15) * 4;
            float4 v = *(const float4*)&A[(size_t)m*512 + k0 + kq];
            float s = msc[m];
            unsigned long long pk =
                  (unsigned long long)f2b(v.x*s)
                | ((unsigned long long)f2b(v.y*s) << 16)
                | ((unsigned long long)f2b(v.z*s) << 32)
                | ((unsigned long long)f2b(v.w*s) << 48);
            *(unsigned long long*)&As[m][kq] = pk;
        }
        if(BT){
            #pragma unroll
            for(int r = 0; r < 4; r++){
                int gi = tid + r*256;
                int n = gi >> 3, ck = (gi & 7) * 8;
                *(int4*)&Bs[n][ck] = *(const int4*)&Lb[(size_t)(n0+n)*512 + k0 + ck];
            }
        } else {
            #pragma unroll
            for(int r = 0; r < 4; r++){
                int nb = (w*4 + r)*8;
                unsigned short tmp[8];
                *(int4*)tmp = *(const int4*)&Lb[(size_t)(k0+lane)*512 + n0 + nb];
                #pragma unroll
                for(int j=0;j<8;j++) Bs[nb+j][lane] = tmp[j];
            }
        }
        __syncthreads();
        #pragma unroll
        for(int kh = 0; kh < 2; kh++){
            bf16x8 av[4], bv[4];
            #pragma unroll
            for(int f=0;f<4;f++){
                av[f] = *(const bf16x8*)&As[wm + f*16 + lr][kh*32 + lg*8];
                bv[f] = *(const bf16x8*)&Bs[wn + f*16 + lr][kh*32 + lg*8];
            }
            #pragma unroll
            for(int mf=0;mf<4;mf++)
                #pragma unroll
                for(int nf=0;nf<4;nf++)
                    acc[mf][nf] = __builtin_amdgcn_mfma_f32_16x16x32_bf16(
                                      av[mf], bv[nf], acc[mf][nf], 0, 0, 0);
        }
        __syncthreads();
    }
    #pragma unroll
    for(int mf=0;mf<4;mf++){
        #pragma unroll
        for(int nf=0;nf<4;nf++){
            #pragma unroll
            for(int r=0;r<4;r++){
                int m = wm + mf*16 + lg*4 + r;
                int n = n0 + wn + nf*16 + lr;
                C[(size_t)m*512 + n] = acc[mf][nf][r];
            }
        }
    }
}

// ---- L epilogue on bf16 tanh(L) rows ----
__global__ void e_modeL_b16(__hip_bfloat16* __restrict__ X){
    int row = blockIdx.x;
    __hip_bfloat16* p = X + (size_t)row*512;
    int t = threadIdx.x;
    float v0 = __bfloat162float(p[t]);
    float v1 = __bfloat162float(p[t+256]);
    __shared__ float sm[4];
    float ss = block_sum<4>(v0*v0 + v1*v1, sm);
    float un = fmaxf(sqrtf(ss), MINV);
    float pn = fminf(tanhf(un), MAXN);
    float f = artanh_f(pn)/un;
    p[t] = __float2bfloat16(f*v0);
    p[t+256] = __float2bfloat16(f*v1);
}

// ---- proj rows (len 512) in place + store logmap factor ----
__global__ void e3_projrow(float* __restrict__ X, float* __restrict__ lf){
    int row = blockIdx.x;
    float* p = X + (size_t)row*512;
    int t = threadIdx.x;
    float v0 = p[t], v1 = p[t+256];
    __shared__ float sm[4];
    float ss = block_sum<4>(v0*v0 + v1*v1, sm);
    float n = fmaxf(sqrtf(ss), MINV);
    if(n > MAXN){ float ps = MAXN/n; p[t] = v0*ps; p[t+256] = v1*ps; }
    float m = fminf(n, MAXN);
    if(t == 0) lf[row] = artanh_f(m)/m;
}

// ---- H epilogue chain ----
__global__ void e_chain(float* __restrict__ Y, const float* __restrict__ X){
    int row = blockIdx.x;               // b*128 + k
    __shared__ float sm[8];
    int t = threadIdx.x;                // 0..511
    size_t rowoff = (size_t)row*512;
    float acc = Y[rowoff + t];
    float ss = block_sum<8>(acc*acc, sm);
    float un = fmaxf(sqrtf(ss), MINV);
    float y = fminf(tanhf(un), MAXN)/un * acc;
    float x = X[rowoff + t];
    float x2 = block_sum<8>(x*x, sm);
    float y2 = block_sum<8>(y*y, sm);
    float xy = block_sum<8>(x*y, sm);
    float a  = 1.f + 2.f*xy + y2;
    float bb = 1.f - x2;
    float den = fmaxf(1.f + 2.f*xy + x2*y2, MINV);
    float z = (a*x + bb*y)/den;
    float zz = block_sum<8>(z*z, sm);
    float n = fmaxf(sqrtf(zz), MINV);
    float ps = (n > MAXN) ? MAXN/n : 1.f;
    float mm = fminf(n, MAXN);
    float lf2 = artanh_f(mm)/mm * ps;
    float v = tanhf(lf2*z);
    float vv = block_sum<8>(v*v, sm);
    float un2 = fmaxf(sqrtf(vv), MINV);
    float f2 = fminf(tanhf(un2), MAXN)/un2;
    Y[rowoff + t] = f2*v;
}

// ---- attention (f32 out) ----
__global__ void att2(const float* __restrict__ H, const float* __restrict__ wh,
                     float* __restrict__ alog, float* __restrict__ outAtt){
    int b = blockIdx.x;
    int tid = threadIdx.x;
    __shared__ float whl[128];
    __shared__ float red[256];
    if(tid < 128) whl[tid] = wh[tid];
    __syncthreads();
    float res2[2];
    #pragma unroll
    for(int h = 0; h < 2; h++){
        int s = tid + h*256;
        const float* hp = H + (size_t)b*65536 + s;
        float mx = 0.f, x2 = 0.f;
        for(int k = 0; k < 128; k++){
            float v = hp[(size_t)k*512];
            mx = fmaf(whl[k], v, mx);
            x2 = fmaf(v, v, x2);
        }
        float xn  = fmaxf(sqrtf(x2), MINV);
        float mxn = fmaxf(fabsf(mx), MINV);
        float t1 = tanhf(mxn/xn * artanh_f(xn));
        res2[h] = t1 * (mx/mxn);
    }
    float rr = tree_sum256(res2[0]*res2[0] + res2[1]*res2[1], red);
    float n = fmaxf(sqrtf(rr), MINV);
    float ps = (n > MAXN) ? MAXN/n : 1.f;
    float m = fminf(n, MAXN);
    float lfw = artanh_f(m)/m * ps;
    float w0 = lfw*res2[0], w1 = lfw*res2[1];
    float wmax = tree_max256(fmaxf(w0, w1), red);
    float e0 = expf(w0 - wmax), e1 = expf(w1 - wmax);
    float es = tree_sum256(e0 + e1, red);
    float p0 = e0/es, p1 = e1/es;
    float pp = tree_sum256(p0*p0 + p1*p1, red);
    float un = fmaxf(sqrtf(pp), MINV);
    float th = tanhf(un);
    float f = fminf(th, MAXN)/un;
    float A0 = f*p0, A1 = f*p1;
    outAtt[b*512 + tid]       = A0;
    outAtt[b*512 + tid + 256] = A1;
    float m2 = fmaxf(fminf(th, MAXN), MINV);
    float fl = artanh_f(m2)/m2;
    alog[b*512 + tid]       = fl*A0;
    alog[b*512 + tid + 256] = fl*A1;
}

// ---- co kernel ----
__global__ void co2(const float* __restrict__ Srep, const float* __restrict__ Crep,
                    const float* __restrict__ alog_s, const float* __restrict__ alog_c,
                    float* __restrict__ out){
    int b = blockIdx.x, tid = threadIdx.x;
    __shared__ float ws_[512], wc_[512];
    #pragma unroll
    for(int h = 0; h < 2; h++){
        int s = tid + h*256;
        const float* sp = Srep + (size_t)(b*512 + s)*100;
        const float* cp = Crep + (size_t)(b*512 + s)*100;
        float s2 = 0.f, c2 = 0.f;
        for(int d = 0; d < 100; d++){
            float a = sp[d]; s2 = fmaf(a, a, s2);
            float e = cp[d]; c2 = fmaf(e, e, c2);
        }
        float nsr = fmaxf(sqrtf(s2), MINV);
        float ncr = fmaxf(sqrtf(c2), MINV);
        ws_[s] = alog_s[b*512 + s] * (artanh_f(nsr)/nsr);
        wc_[s] = alog_c[b*512 + s] * (artanh_f(ncr)/ncr);
    }
    __syncthreads();
    if(tid < 100){
        float acc = 0.f;
        const float* rp = Srep + (size_t)b*51200 + tid;
        for(int s = 0; s < 512; s++) acc = fmaf(ws_[s], rp[(size_t)s*100], acc);
        out[b*200 + tid] = acc;
    } else if(tid >= 128 && tid < 228){
        int d = tid - 128;
        float acc = 0.f;
        const float* rp = Crep + (size_t)b*51200 + d;
        for(int s = 0; s < 512; s++) acc = fmaf(wc_[s], rp[(size_t)s*100], acc);
        out[b*200 + 100 + d] = acc;
    }
}

// ---- diagnostic fill (f32) ----
__global__ void k_fill(float* out, int n, float v){
    int i = blockIdx.x*256 + threadIdx.x;
    if(i < n) out[i] = v;
}

extern "C" void kernel_launch(void* const* d_in, const int* in_sizes, int n_in,
                              void* d_out, int out_size, void* d_ws, size_t ws_size,
                              hipStream_t stream)
{
    const float* Srep = (const float*)d_in[0];   // sentence_rep
    const float* Crep = (const float*)d_in[1];   // comment_rep
    const float* Wl   = (const float*)d_in[2];
    const float* Wc   = (const float*)d_in[3];
    const float* Ws   = (const float*)d_in[4];
    const float* whs  = (const float*)d_in[5];
    const float* whc  = (const float*)d_in[6];
    float* out = (float*)d_out;                  // fp32 output

    bool ok = (n_in == 7) &&
              in_sizes[0] == 6553600 && in_sizes[1] == 6553600 &&
              in_sizes[2] == 10000   && in_sizes[3] == 12800 &&
              in_sizes[4] == 12800   && in_sizes[5] == 128 && in_sizes[6] == 128 &&
              out_size == 156672;
    if(!ok){
        k_fill<<<(out_size+255)/256, 256, 0, stream>>>(out, out_size, 1.0f);
        return;
    }

    const size_t L_E_BYTES  = (size_t)128*512*512*2;     // 67.1 MB bf16
    const size_t A1G_ELTS   = (size_t)128*512*100;
    const size_t HBUF_ELTS  = (size_t)128*128*512;
    const size_t SMALL_ELTS = 6*16384 + 7*65536;
    const size_t REQ = L_E_BYTES + (A1G_ELTS + 4*HBUF_ELTS + SMALL_ELTS)*4;  // ~230 MB
    if(ws_size < REQ){
        k_fill<<<(out_size+255)/256, 256, 0, stream>>>(out, out_size, -1.0f);
        return;
    }

    char* base = (char*)d_ws;
    __hip_bfloat16* L_e = (__hip_bfloat16*)base;
    float* fbase = (float*)(base + L_E_BYTES);
    size_t o = 0;
    float* A1g    = fbase + o; o += A1G_ELTS;
    float* Hsa    = fbase + o; o += HBUF_ELTS;   // Hs_a (chain for Hs; log-src for Hc_b)
    float* Hsb0   = fbase + o; o += HBUF_ELTS;   // Hc_a (chain for Hc; log-src for Hs_b)
    float* Ys     = fbase + o; o += HBUF_ELTS;
    float* Yc     = fbase + o; o += HBUF_ELTS;
    float* scale_s = fbase + o; o += 16384;
    float* g_s     = fbase + o; o += 16384;
    float* scale_c = fbase + o; o += 16384;
    float* g_c     = fbase + o; o += 16384;
    float* lfA     = fbase + o; o += 16384;
    float* lfB     = fbase + o; o += 16384;
    float* xnsc_s  = fbase + o; o += 65536;
    float* xnsc_c  = fbase + o; o += 65536;
    float* xnraw_c = fbase + o; o += 65536;
    float* alog_s  = fbase + o; o += 65536;
    float* alog_c  = fbase + o; o += 65536;

    // stats
    k_colnorm<<<dim3(128,2), 512, 0, stream>>>(Srep, Crep, scale_s, g_s, scale_c, g_c);
    k_rowstats<<<dim3(65536,2), 128, 0, stream>>>(Srep, Crep, scale_s, scale_c,
                                                  xnsc_s, xnsc_c, xnraw_c);
    // A1g = logmap0(proj(mobius_matvec(Wl, comment_rep))) .* g_s  (tiled GEMM + fused epi)
    gemm_wl<<<dim3(4,128), 256, 0, stream>>>(Crep, Wl, xnraw_c, g_s, A1g);
    // GEMM1 via MFMA: L_e(bf16) = tanh(A1g @ Srep^T), then row rescale
    gemm_L_mfma<<<dim3(4,4,128), 256, 0, stream>>>(A1g, Srep, L_e);
    e_modeL_b16<<<65536, 256, 0, stream>>>(L_e);
    // Hs_a / Hc_a bases via fused GEMM+norm+transpose
    gemm_mvw<<<dim3(4,256), 256, 0, stream>>>(Srep, Crep, scale_s, scale_c,
                                              xnsc_s, xnsc_c, Ws, Wc, Hsa, Hsb0);
    e3_projrow<<<16384, 256, 0, stream>>>(Hsa, lfA);
    e3_projrow<<<16384, 256, 0, stream>>>(Hsb0, lfB);
    // merged H GEMMs via MFMA (z=0: NN -> Ys, z=1: NT -> Yc)
    gemm_h_mfma<<<dim3(4,128,2), 256, 0, stream>>>(Hsa, Hsb0, lfA, lfB, L_e, Ys, Yc);
    // H chains (in-place)
    e_chain<<<16384, 512, 0, stream>>>(Ys, Hsa);
    e_chain<<<16384, 512, 0, stream>>>(Yc, Hsb0);
    // attentions + outputs
    att2<<<128, 256, 0, stream>>>(Ys, whs, alog_s, out + 25600);
    att2<<<128, 256, 0, stream>>>(Yc, whc, alog_c, out + 25600 + 65536);
    co2<<<128, 256, 0, stream>>>(Srep, Crep, alog_s, alog_c, out);
    (void)in_sizes; (void)n_in; (void)ws_size;
}

// Round 15
// 805.590 us; speedup vs baseline: 4.6560x; 1.0732x over previous
//
#include <hip/hip_runtime.h>
#include <hip/hip_bf16.h>
#include <math.h>

#define MINV 1e-15f
#define MAXN 0.996f   // (1 - 4e-3) / sqrt(c), c = 1

typedef __attribute__((ext_vector_type(8))) short bf16x8;
typedef __attribute__((ext_vector_type(4))) float f32x4;

__device__ __forceinline__ float artanh_f(float x){
    x = fminf(fmaxf(x, -1.0f + 1e-7f), 1.0f - 1e-7f);
    return 0.5f * (log1pf(x) - log1pf(-x));
}

__device__ __forceinline__ unsigned short f2b(float x){
    __hip_bfloat16 h = __float2bfloat16(x);
    return *reinterpret_cast<unsigned short*>(&h);
}

template<int NW>
__device__ __forceinline__ float block_sum(float v, float* sm){
    #pragma unroll
    for(int o=32;o>0;o>>=1) v += __shfl_down(v,o);
    int lane = threadIdx.x & 63, w = threadIdx.x >> 6;
    if(lane==0) sm[w] = v;
    __syncthreads();
    if(w==0){
        float t = (lane<NW)? sm[lane] : 0.0f;
        #pragma unroll
        for(int o=32;o>0;o>>=1) t += __shfl_down(t,o);
        if(lane==0) sm[0] = t;
    }
    __syncthreads();
    float r = sm[0];
    __syncthreads();
    return r;
}

// ---- fused 3-way block sum for 512-thread blocks (NW=8 waves) ----
template<int NW>
__device__ __forceinline__ void block_sum3(float &va, float &vb, float &vc, float* sm){
    #pragma unroll
    for(int o=32;o>0;o>>=1){
        va += __shfl_down(va,o);
        vb += __shfl_down(vb,o);
        vc += __shfl_down(vc,o);
    }
    int lane = threadIdx.x & 63, w = threadIdx.x >> 6;
    if(lane==0){ sm[w] = va; sm[NW+w] = vb; sm[2*NW+w] = vc; }
    __syncthreads();
    if(w==0){
        float ta = (lane<NW)? sm[lane]      : 0.f;
        float tb = (lane<NW)? sm[NW+lane]   : 0.f;
        float tc = (lane<NW)? sm[2*NW+lane] : 0.f;
        #pragma unroll
        for(int o=NW>>1;o>0;o>>=1){
            ta += __shfl_down(ta,o);
            tb += __shfl_down(tb,o);
            tc += __shfl_down(tc,o);
        }
        if(lane==0){ sm[0]=ta; sm[1]=tb; sm[2]=tc; }
    }
    __syncthreads();
    va = sm[0]; vb = sm[1]; vc = sm[2];
    __syncthreads();
}

// ---- LDS-tree reductions for 256-thread blocks ----
__device__ __forceinline__ float tree_sum256(float v, float* red){
    int tid = threadIdx.x;
    __syncthreads();
    red[tid] = v;
    __syncthreads();
    for(int o = 128; o > 0; o >>= 1){
        if(tid < o) red[tid] += red[tid + o];
        __syncthreads();
    }
    return red[0];
}
__device__ __forceinline__ float tree_max256(float v, float* red){
    int tid = threadIdx.x;
    __syncthreads();
    red[tid] = v;
    __syncthreads();
    for(int o = 128; o > 0; o >>= 1){
        if(tid < o) red[tid] = fmaxf(red[tid], red[tid + o]);
        __syncthreads();
    }
    return red[0];
}

// ---- per-(b,d) column stats over the 512 positions (s_t / c_t proj+logmap) ----
__global__ void k_colnorm(const float* __restrict__ Srep, const float* __restrict__ Crep,
                          float* scale_s, float* g_s, float* scale_c, float* g_c){
    int b = blockIdx.x;
    bool isC = (blockIdx.y == 1);
    const float* X = isC ? Crep : Srep;
    float* sc = isC ? scale_c : scale_s;
    float* gg = isC ? g_c : g_s;
    int d = threadIdx.x & 127, grp = threadIdx.x >> 7;
    float acc = 0.f;
    if(d < 100){
        const float* base = X + (size_t)b*512*100 + d;
        for(int s = grp; s < 512; s += 4){ float x = base[(size_t)s*100]; acc += x*x; }
    }
    __shared__ float sm[4][128];
    sm[grp][d] = acc;
    __syncthreads();
    if(grp == 0){
        if(d < 100){
            float tot = sm[0][d]+sm[1][d]+sm[2][d]+sm[3][d];
            float n1 = fmaxf(sqrtf(tot), MINV);
            float scale = (n1 > MAXN) ? MAXN/n1 : 1.0f;
            float pn = fminf(n1, MAXN);
            sc[b*128+d] = scale;
            gg[b*128+d] = artanh_f(pn)/pn * scale;
        } else {
            sc[b*128+d] = 0.f;
            gg[b*128+d] = 0.f;
        }
    }
}

// ---- per-row (over D=100) stats: scaled norm (for matvec) + raw norm (for Wl) ----
__global__ void k_rowstats(const float* __restrict__ Srep, const float* __restrict__ Crep,
                           const float* __restrict__ scale_s, const float* __restrict__ scale_c,
                           float* xnsc_s, float* xnsc_c, float* xnraw_c){
    int row = blockIdx.x;               // b*512 + s
    bool isC = (blockIdx.y == 1);
    const float* X = (isC ? Crep : Srep) + (size_t)row*100;
    const float* sc = (isC ? scale_c : scale_s) + (size_t)(row >> 9)*128;
    int d = threadIdx.x;
    float xr = 0.f, xs = 0.f;
    if(d < 100){ float v = X[d]; xr = v*v; float w = sc[d]*v; xs = w*w; }
    __shared__ float sm[2];
    float r2 = block_sum<2>(xr, sm);
    float s2 = block_sum<2>(xs, sm);
    if(threadIdx.x == 0){
        float nr = fmaxf(sqrtf(r2), MINV);
        float ns = fmaxf(sqrtf(s2), MINV);
        if(isC){ xnsc_c[row] = ns; xnraw_c[row] = nr; }
        else   { xnsc_s[row] = ns; }
    }
}

// ---- Wl mobius_matvec as tiled GEMM + fused q/g_s epilogue -> A1g [B,512,100] ----
__global__ __launch_bounds__(256) void gemm_wl(
    const float* __restrict__ Crep, const float* __restrict__ Wl,
    const float* __restrict__ xnraw_c, const float* __restrict__ g_s,
    float* __restrict__ A1g)
{
    int b = blockIdx.y;
    int m0 = blockIdx.x*128;
    const float* A = Crep + (size_t)b*51200;
    __shared__ float As[32][132];
    __shared__ float Bs[32][132];
    float acc[8][8];
    #pragma unroll
    for(int i=0;i<8;i++)
        #pragma unroll
        for(int j=0;j<8;j++) acc[i][j] = 0.f;
    int tid = threadIdx.x;
    int ty = tid >> 4, tx = tid & 15;
    for(int k0 = 0; k0 < 100; k0 += 32){
        for(int idx = tid; idx < 4096; idx += 256){
            int kc = idx & 31;
            int mm = idx >> 5;
            int gk = k0 + kc;
            As[kc][mm] = (gk < 100) ? A[(size_t)(m0+mm)*100 + gk] : 0.f;
        }
        for(int idx = tid; idx < 4096; idx += 256){
            int kc = idx & 31;
            int nn = idx >> 5;
            int gk = k0 + kc;
            Bs[kc][nn] = (gk < 100 && nn < 100) ? Wl[(size_t)nn*100 + gk] : 0.f;
        }
        __syncthreads();
        #pragma unroll 4
        for(int kc = 0; kc < 32; kc++){
            float a[8], bb[8];
            *(float4*)&a[0] = *(const float4*)&As[kc][ty*8];
            *(float4*)&a[4] = *(const float4*)&As[kc][ty*8+4];
            *(float4*)&bb[0] = *(const float4*)&Bs[kc][tx*8];
            *(float4*)&bb[4] = *(const float4*)&Bs[kc][tx*8+4];
            #pragma unroll
            for(int i=0;i<8;i++)
                #pragma unroll
                for(int j=0;j<8;j++)
                    acc[i][j] = fmaf(a[i], bb[j], acc[i][j]);
        }
        __syncthreads();
    }
    const float* xnb = xnraw_c + (size_t)b*512;
    const float* gsb = g_s + (size_t)b*128;
    #pragma unroll
    for(int i=0;i<8;i++){
        float ss = 0.f;
        #pragma unroll
        for(int j=0;j<8;j++) ss = fmaf(acc[i][j], acc[i][j], ss);
        ss += __shfl_xor(ss, 1);
        ss += __shfl_xor(ss, 2);
        ss += __shfl_xor(ss, 4);
        ss += __shfl_xor(ss, 8);
        int m = m0 + ty*8 + i;
        float mxn = fmaxf(sqrtf(ss), MINV);
        float xn = xnb[m];
        float t1 = tanhf(mxn/xn * artanh_f(xn));
        float ps = (t1 > MAXN) ? MAXN/t1 : 1.0f;
        float mm = fmaxf(fminf(t1, MAXN), MINV);
        float q = (t1/mxn) * ps * (artanh_f(mm)/mm);
        float* orow = A1g + ((size_t)b*512 + m)*100;
        #pragma unroll
        for(int j=0;j<8;j++){
            int n = tx*8 + j;
            if(n < 100) orow[n] = q*acc[i][j]*gsb[n];
        }
    }
}

// ---- GEMM1 via MFMA: L_e(bf16) = tanh( A1g[b] @ Srep[b]^T ), K=100 padded to 128 ----
__global__ __launch_bounds__(256) void gemm_L_mfma(
    const float* __restrict__ A1g, const float* __restrict__ Srep,
    __hip_bfloat16* __restrict__ L_e)
{
    int b = blockIdx.z;
    int m0 = blockIdx.y * 128, n0 = blockIdx.x * 128;
    const float* Ab = A1g + (size_t)b*51200;
    const float* Bb = Srep + (size_t)b*51200;
    unsigned short* Cb = (unsigned short*)L_e + (size_t)b*262144;

    __shared__ unsigned short As[128][72];
    __shared__ unsigned short Bs[128][72];

    int tid = threadIdx.x;
    int lane = tid & 63, w = tid >> 6;
    int wm = (w >> 1) * 64, wn = (w & 1) * 64;
    int lr = lane & 15, lg = lane >> 4;

    f32x4 acc[4][4];
    #pragma unroll
    for(int i=0;i<4;i++)
        #pragma unroll
        for(int j=0;j<4;j++) acc[i][j] = (f32x4){0.f,0.f,0.f,0.f};

    for(int k0 = 0; k0 < 128; k0 += 64){
        #pragma unroll
        for(int r = 0; r < 8; r++){
            int gi = tid + r*256;
            int m = gi >> 4, kq = (gi & 15) * 4;
            int gk = k0 + kq;
            float4 v = {0.f,0.f,0.f,0.f};
            if(gk < 100) v = *(const float4*)&Ab[(size_t)(m0+m)*100 + gk];
            unsigned long long pk =
                  (unsigned long long)f2b(v.x)
                | ((unsigned long long)f2b(v.y) << 16)
                | ((unsigned long long)f2b(v.z) << 32)
                | ((unsigned long long)f2b(v.w) << 48);
            *(unsigned long long*)&As[m][kq] = pk;
        }
        #pragma unroll
        for(int r = 0; r < 8; r++){
            int gi = tid + r*256;
            int n = gi >> 4, kq = (gi & 15) * 4;
            int gk = k0 + kq;
            float4 v = {0.f,0.f,0.f,0.f};
            if(gk < 100) v = *(const float4*)&Bb[(size_t)(n0+n)*100 + gk];
            unsigned long long pk =
                  (unsigned long long)f2b(v.x)
                | ((unsigned long long)f2b(v.y) << 16)
                | ((unsigned long long)f2b(v.z) << 32)
                | ((unsigned long long)f2b(v.w) << 48);
            *(unsigned long long*)&Bs[n][kq] = pk;
        }
        __syncthreads();
        #pragma unroll
        for(int kh = 0; kh < 2; kh++){
            bf16x8 av[4], bv[4];
            #pragma unroll
            for(int f=0;f<4;f++){
                av[f] = *(const bf16x8*)&As[wm + f*16 + lr][kh*32 + lg*8];
                bv[f] = *(const bf16x8*)&Bs[wn + f*16 + lr][kh*32 + lg*8];
            }
            #pragma unroll
            for(int mf=0;mf<4;mf++)
                #pragma unroll
                for(int nf=0;nf<4;nf++)
                    acc[mf][nf] = __builtin_amdgcn_mfma_f32_16x16x32_bf16(
                                      av[mf], bv[nf], acc[mf][nf], 0, 0, 0);
        }
        __syncthreads();
    }
    #pragma unroll
    for(int mf=0;mf<4;mf++){
        #pragma unroll
        for(int nf=0;nf<4;nf++){
            #pragma unroll
            for(int r=0;r<4;r++){
                int m = m0 + wm + mf*16 + lg*4 + r;
                int n = n0 + wn + nf*16 + lr;
                Cb[(size_t)m*512 + n] = f2b(tanhf(acc[mf][nf][r]));
            }
        }
    }
}

// ---- mobius_matvec(W, scaled rep) fused GEMM + norm + coalesced transpose ----
__global__ __launch_bounds__(256) void gemm_mvw(
    const float* __restrict__ SrepG, const float* __restrict__ CrepG,
    const float* __restrict__ scale_s, const float* __restrict__ scale_c,
    const float* __restrict__ xnsc_s, const float* __restrict__ xnsc_c,
    const float* __restrict__ Ws, const float* __restrict__ Wc,
    float* __restrict__ OutS, float* __restrict__ OutC)
{
    int zz = blockIdx.y;
    int isC = (zz >= 128);
    int b = isC ? zz - 128 : zz;
    const float* A  = (isC ? CrepG : SrepG) + (size_t)b*51200;
    const float* sc = (isC ? scale_c : scale_s) + (size_t)b*128;
    const float* xn = (isC ? xnsc_c : xnsc_s) + (size_t)b*512;
    const float* W  = isC ? Wc : Ws;
    float* Out = (isC ? OutC : OutS) + (size_t)b*65536;
    int m0 = blockIdx.x*128;
    __shared__ float As[32][132];
    __shared__ float Bs[32][132];
    float acc[8][8];
    #pragma unroll
    for(int i=0;i<8;i++)
        #pragma unroll
        for(int j=0;j<8;j++) acc[i][j] = 0.f;
    int tid = threadIdx.x;
    int ty = tid >> 4, tx = tid & 15;
    for(int k0 = 0; k0 < 100; k0 += 32){
        for(int idx = tid; idx < 4096; idx += 256){
            int kc = idx & 31;
            int mm = idx >> 5;
            int gk = k0 + kc;
            float v = 0.f;
            if(gk < 100) v = A[(size_t)(m0+mm)*100 + gk] * sc[gk];
            As[kc][mm] = v;
        }
        for(int idx = tid; idx < 4096; idx += 256){
            int kc = idx & 31;
            int nn = idx >> 5;
            int gk = k0 + kc;
            float v = 0.f;
            if(gk < 100) v = W[(size_t)nn*100 + gk];
            Bs[kc][nn] = v;
        }
        __syncthreads();
        #pragma unroll 4
        for(int kc = 0; kc < 32; kc++){
            float a[8], bb[8];
            *(float4*)&a[0] = *(const float4*)&As[kc][ty*8];
            *(float4*)&a[4] = *(const float4*)&As[kc][ty*8+4];
            *(float4*)&bb[0] = *(const float4*)&Bs[kc][tx*8];
            *(float4*)&bb[4] = *(const float4*)&Bs[kc][tx*8+4];
            #pragma unroll
            for(int i=0;i<8;i++)
                #pragma unroll
                for(int j=0;j<8;j++)
                    acc[i][j] = fmaf(a[i], bb[j], acc[i][j]);
        }
        __syncthreads();
    }
    float mult[8];
    #pragma unroll
    for(int i=0;i<8;i++){
        float ps = 0.f;
        #pragma unroll
        for(int j=0;j<8;j++) ps = fmaf(acc[i][j], acc[i][j], ps);
        ps += __shfl_xor(ps, 1);
        ps += __shfl_xor(ps, 2);
        ps += __shfl_xor(ps, 4);
        ps += __shfl_xor(ps, 8);
        float mxn = fmaxf(sqrtf(ps), MINV);
        float x = xn[m0 + ty*8 + i];
        float t1 = tanhf(mxn/x * artanh_f(x));
        mult[i] = t1/mxn;
    }
    for(int c = 0; c < 4; c++){
        __syncthreads();
        if((tx >> 2) == c){
            #pragma unroll
            for(int j=0;j<8;j++)
                #pragma unroll
                for(int i=0;i<8;i++)
                    Bs[(tx&3)*8 + j][ty*8 + i] = acc[i][j]*mult[i];
        }
        __syncthreads();
        for(int w = tid; w < 4096; w += 256){
            int kr = w >> 7, sl = w & 127;
            Out[(size_t)(c*32 + kr)*512 + m0 + sl] = Bs[kr][sl];
        }
    }
}

// ---- MFMA H GEMMs: z=0 -> Ys = (lfB.*Hsb0[b]) @ L_e[b]      (NN)
//                    z=1 -> Yc = (lfA.*Hsa[b]) @ L_e[b]^T     (NT) ----
__global__ __launch_bounds__(256) void gemm_h_mfma(
    const float* __restrict__ Hsa, const float* __restrict__ Hsb0,
    const float* __restrict__ lfA, const float* __restrict__ lfB,
    const __hip_bfloat16* __restrict__ L_e,
    float* __restrict__ Ys, float* __restrict__ Yc)
{
    int BT = blockIdx.z;
    int b = blockIdx.y;
    int n0 = blockIdx.x * 128;
    const float* A = (BT ? Hsa : Hsb0) + (size_t)b*65536;
    const float* msc = (BT ? lfA : lfB) + (size_t)b*128;
    const unsigned short* Lb = (const unsigned short*)L_e + (size_t)b*262144;
    float* C = (BT ? Yc : Ys) + (size_t)b*65536;

    __shared__ unsigned short As[128][72];
    __shared__ unsigned short Bs[128][72];

    int tid = threadIdx.x;
    int lane = tid & 63, w = tid >> 6;
    int wm = (w >> 1) * 64, wn = (w & 1) * 64;
    int lr = lane & 15, lg = lane >> 4;

    f32x4 acc[4][4];
    #pragma unroll
    for(int i=0;i<4;i++)
        #pragma unroll
        for(int j=0;j<4;j++) acc[i][j] = (f32x4){0.f,0.f,0.f,0.f};

    for(int k0 = 0; k0 < 512; k0 += 64){
        #pragma unroll
        for(int r = 0; r < 8; r++){
            int gi = tid + r*256;
            int m = gi >> 4, kq = (gi & 15) * 4;
            float4 v = *(const float4*)&A[(size_t)m*512 + k0 + kq];
            float s = msc[m];
            unsigned long long pk =
                  (unsigned long long)f2b(v.x*s)
                | ((unsigned long long)f2b(v.y*s) << 16)
                | ((unsigned long long)f2b(v.z*s) << 32)
                | ((unsigned long long)f2b(v.w*s) << 48);
            *(unsigned long long*)&As[m][kq] = pk;
        }
        if(BT){
            #pragma unroll
            for(int r = 0; r < 4; r++){
                int gi = tid + r*256;
                int n = gi >> 3, ck = (gi & 7) * 8;
                *(int4*)&Bs[n][ck] = *(const int4*)&Lb[(size_t)(n0+n)*512 + k0 + ck];
            }
        } else {
            #pragma unroll
            for(int r = 0; r < 4; r++){
                int nb = (w*4 + r)*8;
                unsigned short tmp[8];
                *(int4*)tmp = *(const int4*)&Lb[(size_t)(k0+lane)*512 + n0 + nb];
                #pragma unroll
                for(int j=0;j<8;j++) Bs[nb+j][lane] = tmp[j];
            }
        }
        __syncthreads();
        #pragma unroll
        for(int kh = 0; kh < 2; kh++){
            bf16x8 av[4], bv[4];
            #pragma unroll
            for(int f=0;f<4;f++){
                av[f] = *(const bf16x8*)&As[wm + f*16 + lr][kh*32 + lg*8];
                bv[f] = *(const bf16x8*)&Bs[wn + f*16 + lr][kh*32 + lg*8];
            }
            #pragma unroll
            for(int mf=0;mf<4;mf++)
                #pragma unroll
                for(int nf=0;nf<4;nf++)
                    acc[mf][nf] = __builtin_amdgcn_mfma_f32_16x16x32_bf16(
                                      av[mf], bv[nf], acc[mf][nf], 0, 0, 0);
        }
        __syncthreads();
    }
    #pragma unroll
    for(int mf=0;mf<4;mf++){
        #pragma unroll
        for(int nf=0;nf<4;nf++){
            #pragma unroll
            for(int r=0;r<4;r++){
                int m = wm + mf*16 + lg*4 + r;
                int n = n0 + wn + nf*16 + lr;
                C[(size_t)m*512 + n] = acc[mf][nf][r];
            }
        }
    }
}

// ---- L epilogue on bf16 tanh(L) rows ----
__global__ void e_modeL_b16(__hip_bfloat16* __restrict__ X){
    int row = blockIdx.x;
    __hip_bfloat16* p = X + (size_t)row*512;
    int t = threadIdx.x;
    float v0 = __bfloat162float(p[t]);
    float v1 = __bfloat162float(p[t+256]);
    __shared__ float sm[4];
    float ss = block_sum<4>(v0*v0 + v1*v1, sm);
    float un = fmaxf(sqrtf(ss), MINV);
    float pn = fminf(tanhf(un), MAXN);
    float f = artanh_f(pn)/un;
    p[t] = __float2bfloat16(f*v0);
    p[t+256] = __float2bfloat16(f*v1);
}

// ---- proj rows (len 512) in place + store logmap factor ----
__global__ void e3_projrow(float* __restrict__ X, float* __restrict__ lf){
    int row = blockIdx.x;
    float* p = X + (size_t)row*512;
    int t = threadIdx.x;
    float v0 = p[t], v1 = p[t+256];
    __shared__ float sm[4];
    float ss = block_sum<4>(v0*v0 + v1*v1, sm);
    float n = fmaxf(sqrtf(ss), MINV);
    if(n > MAXN){ float ps = MAXN/n; p[t] = v0*ps; p[t+256] = v1*ps; }
    float m = fminf(n, MAXN);
    if(t == 0) lf[row] = artanh_f(m)/m;
}

// ---- H epilogue chain, ANALYTIC: only 2 reduction passes.
// y = f*acc (f scalar) => y2 = f^2*SS, xy = f*XC;
// z = (a*x + bb*y)/den  => zz = (a^2*X2 + 2*a*bb*f*XC + bb^2*f^2*SS)/den^2.
// Only vv = sum(tanh(lf2*z)^2) needs a second reduction (nonlinear). ----
__global__ void e_chain(float* __restrict__ Y, const float* __restrict__ X){
    int row = blockIdx.x;               // b*128 + k
    __shared__ float sm[24];
    int t = threadIdx.x;                // 0..511
    size_t rowoff = (size_t)row*512;
    float acc = Y[rowoff + t];
    float x   = X[rowoff + t];
    float ssl = acc*acc, x2l = x*x, xcl = x*acc;
    block_sum3<8>(ssl, x2l, xcl, sm);   // -> SS, X2, XC (totals in all threads)
    float SS = ssl, X2 = x2l, XC = xcl;
    float un = fmaxf(sqrtf(SS), MINV);
    float f = fminf(tanhf(un), MAXN)/un;
    float y2 = f*f*SS;
    float xy = f*XC;
    float a  = 1.f + 2.f*xy + y2;
    float bb = 1.f - X2;
    float den = fmaxf(1.f + 2.f*xy + X2*y2, MINV);
    float z = (a*x + bb*f*acc)/den;
    float zz = (a*a*X2 + 2.f*a*bb*f*XC + bb*bb*f*f*SS)/(den*den);
    float n = fmaxf(sqrtf(zz), MINV);
    float ps = (n > MAXN) ? MAXN/n : 1.f;
    float mm = fminf(n, MAXN);
    float lf2 = artanh_f(mm)/mm * ps;
    float v = tanhf(lf2*z);
    float vv = block_sum<8>(v*v, sm);
    float un2 = fmaxf(sqrtf(vv), MINV);
    float f2 = fminf(tanhf(un2), MAXN)/un2;
    Y[rowoff + t] = f2*v;
}

// ---- attention (f32 out) ----
__global__ void att2(const float* __restrict__ H, const float* __restrict__ wh,
                     float* __restrict__ alog, float* __restrict__ outAtt){
    int b = blockIdx.x;
    int tid = threadIdx.x;
    __shared__ float whl[128];
    __shared__ float red[256];
    if(tid < 128) whl[tid] = wh[tid];
    __syncthreads();
    float res2[2];
    #pragma unroll
    for(int h = 0; h < 2; h++){
        int s = tid + h*256;
        const float* hp = H + (size_t)b*65536 + s;
        float mx = 0.f, x2 = 0.f;
        for(int k = 0; k < 128; k++){
            float v = hp[(size_t)k*512];
            mx = fmaf(whl[k], v, mx);
            x2 = fmaf(v, v, x2);
        }
        float xn  = fmaxf(sqrtf(x2), MINV);
        float mxn = fmaxf(fabsf(mx), MINV);
        float t1 = tanhf(mxn/xn * artanh_f(xn));
        res2[h] = t1 * (mx/mxn);
    }
    float rr = tree_sum256(res2[0]*res2[0] + res2[1]*res2[1], red);
    float n = fmaxf(sqrtf(rr), MINV);
    float ps = (n > MAXN) ? MAXN/n : 1.f;
    float m = fminf(n, MAXN);
    float lfw = artanh_f(m)/m * ps;
    float w0 = lfw*res2[0], w1 = lfw*res2[1];
    float wmax = tree_max256(fmaxf(w0, w1), red);
    float e0 = expf(w0 - wmax), e1 = expf(w1 - wmax);
    float es = tree_sum256(e0 + e1, red);
    float p0 = e0/es, p1 = e1/es;
    float pp = tree_sum256(p0*p0 + p1*p1, red);
    float un = fmaxf(sqrtf(pp), MINV);
    float th = tanhf(un);
    float f = fminf(th, MAXN)/un;
    float A0 = f*p0, A1 = f*p1;
    outAtt[b*512 + tid]       = A0;
    outAtt[b*512 + tid + 256] = A1;
    float m2 = fmaxf(fminf(th, MAXN), MINV);
    float fl = artanh_f(m2)/m2;
    alog[b*512 + tid]       = fl*A0;
    alog[b*512 + tid + 256] = fl*A1;
}

// ---- co kernel ----
__global__ void co2(const float* __restrict__ Srep, const float* __restrict__ Crep,
                    const float* __restrict__ alog_s, const float* __restrict__ alog_c,
                    float* __restrict__ out){
    int b = blockIdx.x, tid = threadIdx.x;
    __shared__ float ws_[512], wc_[512];
    #pragma unroll
    for(int h = 0; h < 2; h++){
        int s = tid + h*256;
        const float* sp = Srep + (size_t)(b*512 + s)*100;
        const float* cp = Crep + (size_t)(b*512 + s)*100;
        float s2 = 0.f, c2 = 0.f;
        for(int d = 0; d < 100; d++){
            float a = sp[d]; s2 = fmaf(a, a, s2);
            float e = cp[d]; c2 = fmaf(e, e, c2);
        }
        float nsr = fmaxf(sqrtf(s2), MINV);
        float ncr = fmaxf(sqrtf(c2), MINV);
        ws_[s] = alog_s[b*512 + s] * (artanh_f(nsr)/nsr);
        wc_[s] = alog_c[b*512 + s] * (artanh_f(ncr)/ncr);
    }
    __syncthreads();
    if(tid < 100){
        float acc = 0.f;
        const float* rp = Srep + (size_t)b*51200 + tid;
        for(int s = 0; s < 512; s++) acc = fmaf(ws_[s], rp[(size_t)s*100], acc);
        out[b*200 + tid] = acc;
    } else if(tid >= 128 && tid < 228){
        int d = tid - 128;
        float acc = 0.f;
        const float* rp = Crep + (size_t)b*51200 + d;
        for(int s = 0; s < 512; s++) acc = fmaf(wc_[s], rp[(size_t)s*100], acc);
        out[b*200 + 100 + d] = acc;
    }
}

// ---- diagnostic fill (f32) ----
__global__ void k_fill(float* out, int n, float v){
    int i = blockIdx.x*256 + threadIdx.x;
    if(i < n) out[i] = v;
}

extern "C" void kernel_launch(void* const* d_in, const int* in_sizes, int n_in,
                              void* d_out, int out_size, void* d_ws, size_t ws_size,
                              hipStream_t stream)
{
    const float* Srep = (const float*)d_in[0];   // sentence_rep
    const float* Crep = (const float*)d_in[1];   // comment_rep
    const float* Wl   = (const float*)d_in[2];
    const float* Wc   = (const float*)d_in[3];
    const float* Ws   = (const float*)d_in[4];
    const float* whs  = (const float*)d_in[5];
    const float* whc  = (const float*)d_in[6];
    float* out = (float*)d_out;                  // fp32 output

    bool ok = (n_in == 7) &&
              in_sizes[0] == 6553600 && in_sizes[1] == 6553600 &&
              in_sizes[2] == 10000   && in_sizes[3] == 12800 &&
              in_sizes[4] == 12800   && in_sizes[5] == 128 && in_sizes[6] == 128 &&
              out_size == 156672;
    if(!ok){
        k_fill<<<(out_size+255)/256, 256, 0, stream>>>(out, out_size, 1.0f);
        return;
    }

    const size_t L_E_BYTES  = (size_t)128*512*512*2;     // 67.1 MB bf16
    const size_t A1G_ELTS   = (size_t)128*512*100;
    const size_t HBUF_ELTS  = (size_t)128*128*512;
    const size_t SMALL_ELTS = 6*16384 + 7*65536;
    const size_t REQ = L_E_BYTES + (A1G_ELTS + 4*HBUF_ELTS + SMALL_ELTS)*4;  // ~230 MB
    if(ws_size < REQ){
        k_fill<<<(out_size+255)/256, 256, 0, stream>>>(out, out_size, -1.0f);
        return;
    }

    char* base = (char*)d_ws;
    __hip_bfloat16* L_e = (__hip_bfloat16*)base;
    float* fbase = (float*)(base + L_E_BYTES);
    size_t o = 0;
    float* A1g    = fbase + o; o += A1G_ELTS;
    float* Hsa    = fbase + o; o += HBUF_ELTS;   // Hs_a (chain for Hs; log-src for Hc_b)
    float* Hsb0   = fbase + o; o += HBUF_ELTS;   // Hc_a (chain for Hc; log-src for Hs_b)
    float* Ys     = fbase + o; o += HBUF_ELTS;
    float* Yc     = fbase + o; o += HBUF_ELTS;
    float* scale_s = fbase + o; o += 16384;
    float* g_s     = fbase + o; o += 16384;
    float* scale_c = fbase + o; o += 16384;
    float* g_c     = fbase + o; o += 16384;
    float* lfA     = fbase + o; o += 16384;
    float* lfB     = fbase + o; o += 16384;
    float* xnsc_s  = fbase + o; o += 65536;
    float* xnsc_c  = fbase + o; o += 65536;
    float* xnraw_c = fbase + o; o += 65536;
    float* alog_s  = fbase + o; o += 65536;
    float* alog_c  = fbase + o; o += 65536;

    // stats
    k_colnorm<<<dim3(128,2), 512, 0, stream>>>(Srep, Crep, scale_s, g_s, scale_c, g_c);
    k_rowstats<<<dim3(65536,2), 128, 0, stream>>>(Srep, Crep, scale_s, scale_c,
                                                  xnsc_s, xnsc_c, xnraw_c);
    // A1g (tiled GEMM + fused mobius epilogue)
    gemm_wl<<<dim3(4,128), 256, 0, stream>>>(Crep, Wl, xnraw_c, g_s, A1g);
    // GEMM1 via MFMA: L_e(bf16) = tanh(A1g @ Srep^T), then row rescale
    gemm_L_mfma<<<dim3(4,4,128), 256, 0, stream>>>(A1g, Srep, L_e);
    e_modeL_b16<<<65536, 256, 0, stream>>>(L_e);
    // Hs_a / Hc_a bases via fused GEMM+norm+transpose
    gemm_mvw<<<dim3(4,256), 256, 0, stream>>>(Srep, Crep, scale_s, scale_c,
                                              xnsc_s, xnsc_c, Ws, Wc, Hsa, Hsb0);
    e3_projrow<<<16384, 256, 0, stream>>>(Hsa, lfA);
    e3_projrow<<<16384, 256, 0, stream>>>(Hsb0, lfB);
    // merged H GEMMs via MFMA (z=0: NN -> Ys, z=1: NT -> Yc)
    gemm_h_mfma<<<dim3(4,128,2), 256, 0, stream>>>(Hsa, Hsb0, lfA, lfB, L_e, Ys, Yc);
    // H chains (in-place, analytic reductions)
    e_chain<<<16384, 512, 0, stream>>>(Ys, Hsa);
    e_chain<<<16384, 512, 0, stream>>>(Yc, Hsb0);
    // attentions + outputs
    att2<<<128, 256, 0, stream>>>(Ys, whs, alog_s, out + 25600);
    att2<<<128, 256, 0, stream>>>(Yc, whc, alog_c, out + 25600 + 65536);
    co2<<<128, 256, 0, stream>>>(Srep, Crep, alog_s, alog_c, out);
    (void)in_sizes; (void)n_in; (void)ws_size;
}